// Round 3
// baseline (5402.568 us; speedup 1.0000x reference)
//
#include <hip/hip_runtime.h>
#include <math.h>

#define EPSF 1e-7f
#define MAXNRM 10.0f
#define NB 782          // ceil(100000/128) buckets
#define RPB 128         // rows per bucket

__device__ __forceinline__ float wsum(float v) {
    #pragma unroll
    for (int off = 32; off > 0; off >>= 1) v += __shfl_xor(v, off, 64);
    return v;
}

// ---------------- logmap0 of embeddings -> t ----------------
__global__ void k_logmap(const float* __restrict__ eu, const float* __restrict__ ei,
                         int Nu, int Ntot, float* __restrict__ out) {
    int idx = blockIdx.x * blockDim.x + threadIdx.x;
    if (idx >= Ntot * 64) return;
    int n = idx >> 6, d = idx & 63;
    const float* src = (n < Nu) ? (eu + (size_t)n * 64) : (ei + (size_t)(n - Nu) * 64);
    float x0 = src[0];
    float alpha = fmaxf(x0, 1.0f + EPSF);
    float coef = acoshf(alpha) / sqrtf(fmaxf(alpha * alpha - 1.0f, EPSF));
    out[idx] = (d == 0) ? 0.0f : coef * src[d];
}

// ---------------- MoE ----------------
__global__ __launch_bounds__(256) void k_moe(
    const float* __restrict__ X, float* __restrict__ Y,
    const float* __restrict__ W, const float* __restrict__ Bb,
    const float* __restrict__ GW, const float* __restrict__ GB)
{
    __shared__ float sX[32][68];
    __shared__ float sG[32][8];
    const int tid = threadIdx.x;
    const int n0 = blockIdx.x * 32;

    for (int i = tid; i < 2048; i += 256)
        sX[i >> 6][i & 63] = X[(size_t)n0 * 64 + i];
    __syncthreads();

    {
        const int n = tid >> 3, e = tid & 7;
        float lg = GB[e];
        #pragma unroll 16
        for (int d = 0; d < 64; ++d) lg += sX[n][d] * GW[d * 8 + e];
        sG[n][e] = lg;
    }
    __syncthreads();
    if (tid < 32) {
        float mx = -1e30f;
        #pragma unroll
        for (int e = 0; e < 8; ++e) mx = fmaxf(mx, sG[tid][e]);
        float ex[8]; float s = 0.f;
        #pragma unroll
        for (int e = 0; e < 8; ++e) { ex[e] = expf(sG[tid][e] - mx); s += ex[e]; }
        float inv = 1.0f / s;
        #pragma unroll
        for (int e = 0; e < 8; ++e) sG[tid][e] = ex[e] * inv;
    }
    __syncthreads();

    const int o = tid & 63, nq = tid >> 6;
    float y[8][8];
    #pragma unroll
    for (int k = 0; k < 8; ++k)
        #pragma unroll
        for (int e = 0; e < 8; ++e) y[k][e] = 0.f;

    for (int dc = 0; dc < 16; ++dc) {
        float a[8][4];
        #pragma unroll
        for (int k = 0; k < 8; ++k) {
            float4 av = *(const float4*)(&sX[nq + 4 * k][dc * 4]);
            a[k][0] = av.x; a[k][1] = av.y; a[k][2] = av.z; a[k][3] = av.w;
        }
        #pragma unroll
        for (int e = 0; e < 8; ++e) {
            #pragma unroll
            for (int j = 0; j < 4; ++j) {
                const float w = W[(((size_t)e) << 12) + (size_t)(dc * 4 + j) * 64 + o];
                #pragma unroll
                for (int k = 0; k < 8; ++k) y[k][e] += a[k][j] * w;
            }
        }
    }

    #pragma unroll
    for (int k = 0; k < 8; ++k) {
        const int n = nq + 4 * k;
        float acc = 0.f;
        #pragma unroll
        for (int e = 0; e < 8; ++e) acc += sG[n][e] * (y[k][e] + Bb[e * 64 + o]);
        Y[(size_t)(n0 + n) * 64 + o] = acc;
    }
}

// ---------------- VAE mid ----------------
__global__ __launch_bounds__(256) void k_vae(
    const float* __restrict__ M, float* __restrict__ Hout,
    const float* __restrict__ EPSN,
    const float* __restrict__ muW, const float* __restrict__ mub,
    const float* __restrict__ lvW, const float* __restrict__ lvb,
    float* __restrict__ klslot)
{
    __shared__ float sM[32][68];
    __shared__ float sC[32];
    const int tid = threadIdx.x;
    const int n0 = blockIdx.x * 32;

    for (int i = tid; i < 2048; i += 256)
        sM[i >> 6][i & 63] = M[(size_t)n0 * 64 + i];
    __syncthreads();

    const int o = tid & 63, nq = tid >> 6;
    float ymu[8], ylv[8];
    #pragma unroll
    for (int k = 0; k < 8; ++k) { ymu[k] = 0.f; ylv[k] = 0.f; }

    for (int dc = 0; dc < 16; ++dc) {
        float a[8][4];
        #pragma unroll
        for (int k = 0; k < 8; ++k) {
            float4 av = *(const float4*)(&sM[nq + 4 * k][dc * 4]);
            a[k][0] = av.x; a[k][1] = av.y; a[k][2] = av.z; a[k][3] = av.w;
        }
        #pragma unroll
        for (int j = 0; j < 4; ++j) {
            const float wm = muW[(size_t)(dc * 4 + j) * 64 + o];
            const float wl = lvW[(size_t)(dc * 4 + j) * 64 + o];
            #pragma unroll
            for (int k = 0; k < 8; ++k) { ymu[k] += a[k][j] * wm; ylv[k] += a[k][j] * wl; }
        }
    }

    float u[8];
    float klp = 0.f;
    #pragma unroll
    for (int k = 0; k < 8; ++k) {
        const int n = nq + 4 * k;
        const float mu = ymu[k] + mub[o];
        const float lv = ylv[k] + lvb[o];
        const float elv = expf(lv);
        klp += 1.0f + lv - mu * mu - elv;
        u[k] = mu + EPSN[(size_t)(n0 + n) * 64 + o] * expf(0.5f * lv);
    }
    klp = wsum(klp);
    if ((tid & 63) == 0) atomicAdd(&klslot[(blockIdx.x * 4 + nq) & 255], klp);

    __syncthreads();
    #pragma unroll
    for (int k = 0; k < 8; ++k) sM[nq + 4 * k][o] = u[k];
    __syncthreads();

    if (tid < 32) {
        float ss = 0.f;
        for (int d = 1; d < 64; ++d) ss += sM[tid][d] * sM[tid][d];
        const float nr = fmaxf(sqrtf(ss), EPSF);
        const float r = sinhf(nr) / nr;
        const float sn = r * sqrtf(ss);
        const float scale = fminf(1.0f, MAXNRM / fmaxf(sn, EPSF));
        const float mult = r * scale;
        const float s2 = mult * mult * ss;
        const float z0 = sqrtf(1.0f + s2);
        const float alpha = fmaxf(z0, 1.0f + EPSF);
        const float coef = acoshf(alpha) / sqrtf(fmaxf(alpha * alpha - 1.0f, EPSF));
        sC[tid] = coef * mult;
    }
    __syncthreads();

    #pragma unroll
    for (int k = 0; k < 8; ++k) {
        const int n = nq + 4 * k;
        Hout[(size_t)(n0 + n) * 64 + o] = (o == 0) ? 0.f : sC[n] * sM[n][o];
    }
}

// ---------------- FFN ----------------
__global__ __launch_bounds__(256) void k_ffn(
    float* __restrict__ Hio,
    const float* __restrict__ f1W, const float* __restrict__ f1b,
    const float* __restrict__ f2W, const float* __restrict__ f2b)
{
    __shared__ float sH[32][68];
    __shared__ float sH1[32][132];
    const int tid = threadIdx.x;
    const int n0 = blockIdx.x * 32;

    for (int i = tid; i < 2048; i += 256)
        sH[i >> 6][i & 63] = Hio[(size_t)n0 * 64 + i];
    __syncthreads();

    const int o = tid & 63, nq = tid >> 6;
    float y0[8], y1[8];
    #pragma unroll
    for (int k = 0; k < 8; ++k) { y0[k] = 0.f; y1[k] = 0.f; }

    for (int dc = 0; dc < 16; ++dc) {
        float a[8][4];
        #pragma unroll
        for (int k = 0; k < 8; ++k) {
            float4 av = *(const float4*)(&sH[nq + 4 * k][dc * 4]);
            a[k][0] = av.x; a[k][1] = av.y; a[k][2] = av.z; a[k][3] = av.w;
        }
        #pragma unroll
        for (int j = 0; j < 4; ++j) {
            const float w0 = f1W[(size_t)(dc * 4 + j) * 128 + o];
            const float w1 = f1W[(size_t)(dc * 4 + j) * 128 + 64 + o];
            #pragma unroll
            for (int k = 0; k < 8; ++k) { y0[k] += a[k][j] * w0; y1[k] += a[k][j] * w1; }
        }
    }
    #pragma unroll
    for (int k = 0; k < 8; ++k) {
        const int n = nq + 4 * k;
        sH1[n][o] = fmaxf(y0[k] + f1b[o], 0.f);
        sH1[n][64 + o] = fmaxf(y1[k] + f1b[64 + o], 0.f);
    }
    __syncthreads();

    float y2[8];
    #pragma unroll
    for (int k = 0; k < 8; ++k) y2[k] = 0.f;
    for (int dc = 0; dc < 32; ++dc) {
        float a[8][4];
        #pragma unroll
        for (int k = 0; k < 8; ++k) {
            float4 av = *(const float4*)(&sH1[nq + 4 * k][dc * 4]);
            a[k][0] = av.x; a[k][1] = av.y; a[k][2] = av.z; a[k][3] = av.w;
        }
        #pragma unroll
        for (int j = 0; j < 4; ++j) {
            const float w = f2W[(size_t)(dc * 4 + j) * 64 + o];
            #pragma unroll
            for (int k = 0; k < 8; ++k) y2[k] += a[k][j] * w;
        }
    }
    #pragma unroll
    for (int k = 0; k < 8; ++k)
        Hio[(size_t)(n0 + nq + 4 * k) * 64 + o] = y2[k] + f2b[o];
}

// ---------------- recon loss ----------------
__global__ void k_recon(const float* __restrict__ HM, const float* __restrict__ M,
                        int Ntot, float* __restrict__ slot)
{
    const int w = threadIdx.x >> 6, d = threadIdx.x & 63;
    const int n = blockIdx.x * 4 + w;
    if (n >= Ntot) return;
    const float hv = HM[(size_t)n * 64 + d];
    const float mv = M[(size_t)n * 64 + d];
    const float ssh = wsum(d == 0 ? 0.f : hv * hv);
    const float ssm = wsum(d == 0 ? 0.f : mv * mv);

    const float nm = fmaxf(sqrtf(ssm), EPSF);
    const float rm = sinhf(nm) / nm;
    const float em = (d == 0) ? coshf(nm) : rm * mv;

    const float nh = fmaxf(sqrtf(ssh), EPSF);
    const float rh = sinhf(nh) / nh;
    const float sn = rh * sqrtf(ssh);
    const float scale = fminf(1.0f, MAXNRM / fmaxf(sn, EPSF));
    const float mult = rh * scale;
    const float rec = (d == 0) ? sqrtf(1.0f + mult * mult * ssh) : mult * hv;

    const float inner = wsum(d == 0 ? -rec * em : rec * em);
    if (d == 0) {
        const float dd = acoshf(fmaxf(-inner, 1.0f + EPSF));
        atomicAdd(&slot[(blockIdx.x * 4 + w) & 255], dd * dd);
    }
}

// ---------------- bucket histogram ----------------
__global__ __launch_bounds__(256) void k_bhist(const int* __restrict__ rows, int nnz,
                                               int* __restrict__ bhist) {
    __shared__ int h[NB];
    for (int j = threadIdx.x; j < NB; j += 256) h[j] = 0;
    __syncthreads();
    for (int i = blockIdx.x * 256 + threadIdx.x; i < nnz; i += gridDim.x * 256)
        atomicAdd(&h[rows[i] >> 7], 1);
    __syncthreads();
    for (int j = threadIdx.x; j < NB; j += 256)
        if (h[j]) atomicAdd(&bhist[j], h[j]);
}

// ---------------- bucket scan (1 block) ----------------
__global__ __launch_bounds__(1024) void k_bscan(const int* __restrict__ bhist,
                                                int* __restrict__ bstart, int* __restrict__ gcur,
                                                int nnz) {
    __shared__ int s[1024];
    const int tid = threadIdx.x;
    int v = (tid < NB) ? bhist[tid] : 0;
    s[tid] = v;
    __syncthreads();
    for (int off = 1; off < 1024; off <<= 1) {
        int t = (tid >= off) ? s[tid - off] : 0;
        __syncthreads();
        s[tid] += t;
        __syncthreads();
    }
    if (tid < NB) {
        bstart[tid + 1] = s[tid];
        const int excl = s[tid] - v;
        gcur[tid] = excl;
        if (tid == 0) bstart[0] = 0;
    }
}

// ---------------- bucket scatter: (row&127)<<17 | col, val ----------------
__global__ void k_bscatter(const int* __restrict__ rows, const int* __restrict__ cols,
                           const float* __restrict__ vals, int nnz,
                           int* __restrict__ gcur, int2* __restrict__ sedge) {
    int i = blockIdx.x * blockDim.x + threadIdx.x;
    if (i < nnz) {
        const int r = rows[i];
        const int pos = atomicAdd(&gcur[r >> 7], 1);
        int2 e;
        e.x = ((r & 127) << 17) | cols[i];
        e.y = __float_as_int(vals[i]);
        sedge[pos] = e;
    }
}

// ---------------- bucket SpMM: one block per bucket, LDS 128x64 tile ----------------
template <int MODE>
__global__ __launch_bounds__(256) void k_spmm(
    const float* __restrict__ in, float* __restrict__ out, float* __restrict__ osum,
    const int* __restrict__ bstart, const int2* __restrict__ sedge, int Ntot)
{
    __shared__ float sacc[RPB * 64];
    const int tid = threadIdx.x;
    for (int i = tid; i < RPB * 64; i += 256) sacc[i] = 0.f;
    __syncthreads();

    const int w = tid >> 6;
    const int lane = tid & 63;
    const int g = lane >> 4, q = lane & 15;
    const int s = bstart[blockIdx.x], t = bstart[blockIdx.x + 1];

    for (int base = s + w * 16; base < t; base += 64) {
        #pragma unroll
        for (int u = 0; u < 4; ++u) {
            const int e = base + u * 4 + g;
            if (e < t) {
                const int2 ed = sedge[e];
                const float v = __int_as_float(ed.y);
                const int rib = ((unsigned)ed.x) >> 17;
                const int col = ed.x & 0x1FFFF;
                const float4 x = *(const float4*)(in + (((size_t)col) << 6) + q * 4);
                float* dst = &sacc[rib * 64 + q * 4];
                atomicAdd(dst + 0, v * x.x);
                atomicAdd(dst + 1, v * x.y);
                atomicAdd(dst + 2, v * x.z);
                atomicAdd(dst + 3, v * x.w);
            }
        }
    }
    __syncthreads();

    const int r0 = blockIdx.x * RPB;
    for (int i = tid; i < RPB * 16; i += 256) {
        const int row = i >> 4, qq = i & 15;
        const int r = r0 + row;
        if (r >= Ntot) break;
        const float4 acc = *(const float4*)(&sacc[row * 64 + qq * 4]);
        const size_t oi = (((size_t)r) << 6) + qq * 4;
        *(float4*)(out + oi) = acc;
        if (MODE == 0) {
            *(float4*)(osum + oi) = acc;
        } else {
            float4 sv = *(const float4*)(osum + oi);
            sv.x += acc.x; sv.y += acc.y; sv.z += acc.z; sv.w += acc.w;
            *(float4*)(osum + oi) = sv;
        }
    }
}

// ---------------- expmap0(out_sum, project=True) ----------------
__global__ void k_expmap_proj(const float* __restrict__ in, float* __restrict__ out, int Ntot) {
    const int w = threadIdx.x >> 6, d = threadIdx.x & 63;
    const int n = blockIdx.x * 4 + w;
    if (n >= Ntot) return;
    const float v = in[((size_t)n << 6) + d];
    const float ss = wsum(d == 0 ? 0.f : v * v);
    const float nr = fmaxf(sqrtf(ss), EPSF);
    const float r = sinhf(nr) / nr;
    const float sn = r * sqrtf(ss);
    const float scale = fminf(1.0f, MAXNRM / fmaxf(sn, EPSF));
    const float mult = r * scale;
    out[((size_t)n << 6) + d] = (d == 0) ? sqrtf(1.0f + mult * mult * ss) : mult * v;
}

// ---------------- triple margin loss ----------------
__global__ __launch_bounds__(256) void k_triples(
    const float* __restrict__ O, const int* __restrict__ tri,
    int T, float* __restrict__ slot)
{
    const int lane = threadIdx.x & 63;
    const int g = lane >> 4, q = lane & 15;
    const int wid = blockIdx.x * 4 + (threadIdx.x >> 6);
    const int nwaves = gridDim.x * 4;

    float racc = 0.f;
    for (int tb = wid * 4; tb < T; tb += nwaves * 4) {
        const int t = tb + g;
        const int a = tri[3 * t], p = tri[3 * t + 1], nn = tri[3 * t + 2];
        const float4 av = *(const float4*)(O + (((size_t)a) << 6) + q * 4);
        const float4 pv = *(const float4*)(O + (((size_t)p) << 6) + q * 4);
        const float4 nv = *(const float4*)(O + (((size_t)nn) << 6) + q * 4);
        const float s0 = (q == 0) ? -1.f : 1.f;
        float i1 = s0 * av.x * pv.x + av.y * pv.y + av.z * pv.z + av.w * pv.w;
        float i2 = s0 * av.x * nv.x + av.y * nv.y + av.z * nv.z + av.w * nv.w;
        #pragma unroll
        for (int off = 1; off < 16; off <<= 1) {
            i1 += __shfl_xor(i1, off, 64);
            i2 += __shfl_xor(i2, off, 64);
        }
        if (q == 0) {
            const float d1 = acoshf(fmaxf(-i1, 1.0f + EPSF));
            const float d2 = acoshf(fmaxf(-i2, 1.0f + EPSF));
            const float l = d1 * d1 - d2 * d2 + 0.1f;
            if (l > 0.f) racc += l;
        }
    }

    racc = wsum(racc);
    __shared__ float sb[4];
    if (lane == 0) sb[threadIdx.x >> 6] = racc;
    __syncthreads();
    if (threadIdx.x == 0)
        atomicAdd(&slot[blockIdx.x & 255], sb[0] + sb[1] + sb[2] + sb[3]);
}

// ---------------- finalize ----------------
__global__ void k_final(const float* __restrict__ slots, float* __restrict__ out, int Ntot)
{
    const int tid = threadIdx.x;
    float m = slots[tid], r = slots[256 + tid], k = slots[512 + tid];
    m = wsum(m); r = wsum(r); k = wsum(k);
    __shared__ float sm[4], sr[4], sk[4];
    if ((tid & 63) == 0) { sm[tid >> 6] = m; sr[tid >> 6] = r; sk[tid >> 6] = k; }
    __syncthreads();
    if (tid == 0) {
        const float M = sm[0] + sm[1] + sm[2] + sm[3];
        const float R = sr[0] + sr[1] + sr[2] + sr[3];
        const float K = sk[0] + sk[1] + sk[2] + sk[3];
        const float recon = R / (float)Ntot;
        const float kl = -0.5f * K / ((float)Ntot * 64.0f);
        out[0] = M + 0.1f * (recon + kl);
    }
}

extern "C" void kernel_launch(void* const* d_in, const int* in_sizes, int n_in,
                              void* d_out, int out_size, void* d_ws, size_t ws_size,
                              hipStream_t stream)
{
    const float* emb_user = (const float*)d_in[0];
    const float* emb_item = (const float*)d_in[1];
    const int*   adj_rows = (const int*)d_in[2];
    const int*   adj_cols = (const int*)d_in[3];
    const float* adj_vals = (const float*)d_in[4];
    const int*   triples  = (const int*)d_in[5];
    const float* epsin    = (const float*)d_in[6];
    const float* tW  = (const float*)d_in[7];
    const float* tb  = (const float*)d_in[8];
    const float* tgW = (const float*)d_in[9];
    const float* tgb = (const float*)d_in[10];
    const float* muW = (const float*)d_in[11];
    const float* mub = (const float*)d_in[12];
    const float* lvW = (const float*)d_in[13];
    const float* lvb = (const float*)d_in[14];
    const float* f1W = (const float*)d_in[15];
    const float* f1b = (const float*)d_in[16];
    const float* f2W = (const float*)d_in[17];
    const float* f2b = (const float*)d_in[18];
    const float* dW  = (const float*)d_in[19];
    const float* db  = (const float*)d_in[20];
    const float* dgW = (const float*)d_in[21];
    const float* dgb = (const float*)d_in[22];

    const int Nu = in_sizes[0] / 64, Ni = in_sizes[1] / 64;
    const int N = Nu + Ni;            // 100000
    const int NNZ = in_sizes[4];      // 3200000
    const int T = in_sizes[5] / 3;    // 262144

    float* ws = (float*)d_ws;
    size_t off = 0;
    float* slots = ws + off; off += 1024;            // [0..256) margin, [256..512) recon, [512..768) kl
    float* A  = ws + off; off += (size_t)N * 64;     // t / h ; later overlaid with bucketed edges
    float* B  = ws + off; off += (size_t)N * 64;     // m
    float* C  = ws + off; off += (size_t)N * 64;     // hm, then out_sum
    float* Dd = ws + off; off += (size_t)N * 64;     // spmm ping
    float* Ee = ws + off; off += (size_t)N * 64;     // spmm pong, then out
    int* bstart = (int*)(ws + off); off += 1024;     // NB+1
    int* gcur   = (int*)(ws + off); off += 1024;
    int* bhist  = (int*)(ws + off); off += 1024;

    int2* sedge = (int2*)A;            // bucketed (packed,val) [NNZ] = 25.6 MB = N*64*4 bytes

    hipMemsetAsync(slots, 0, 1024 * sizeof(float), stream);
    hipMemsetAsync(bhist, 0, 1024 * sizeof(int), stream);

    const int nb32 = N / 32;          // 3125
    const int nbN4 = (N + 3) / 4;     // 25000

    k_logmap<<<(N * 64 + 255) / 256, 256, 0, stream>>>(emb_user, emb_item, Nu, N, A);
    k_moe<<<nb32, 256, 0, stream>>>(A, B, tW, tb, tgW, tgb);
    k_vae<<<nb32, 256, 0, stream>>>(B, A, epsin, muW, mub, lvW, lvb, slots + 512);
    k_ffn<<<nb32, 256, 0, stream>>>(A, f1W, f1b, f2W, f2b);
    k_moe<<<nb32, 256, 0, stream>>>(A, C, dW, db, dgW, dgb);
    k_recon<<<nbN4, 256, 0, stream>>>(C, B, N, slots + 256);

    k_bhist<<<1024, 256, 0, stream>>>(adj_rows, NNZ, bhist);
    k_bscan<<<1, 1024, 0, stream>>>(bhist, bstart, gcur, NNZ);
    k_bscatter<<<(NNZ + 255) / 256, 256, 0, stream>>>(adj_rows, adj_cols, adj_vals, NNZ, gcur, sedge);

    k_spmm<0><<<NB, 256, 0, stream>>>(B,  Dd, C, bstart, sedge, N);
    k_spmm<1><<<NB, 256, 0, stream>>>(Dd, Ee, C, bstart, sedge, N);
    k_spmm<1><<<NB, 256, 0, stream>>>(Ee, Dd, C, bstart, sedge, N);

    k_expmap_proj<<<nbN4, 256, 0, stream>>>(C, Ee, N);
    k_triples<<<2048, 256, 0, stream>>>(Ee, triples, T, slots);
    k_final<<<1, 256, 0, stream>>>(slots, (float*)d_out, N);
}

// Round 4
// 1040.947 us; speedup vs baseline: 5.1901x; 5.1901x over previous
//
#include <hip/hip_runtime.h>
#include <math.h>

#define EPSF 1e-7f
#define MAXNRM 10.0f
#define NB 782          // ceil(100000/128) buckets
#define RPB 128         // rows per bucket
#define EPT 16          // edges per thread in stage-1 scatter

__device__ __forceinline__ float wsum(float v) {
    #pragma unroll
    for (int off = 32; off > 0; off >>= 1) v += __shfl_xor(v, off, 64);
    return v;
}

__device__ __forceinline__ unsigned short f2bf(float x) {   // RNE
    unsigned u = __float_as_uint(x);
    unsigned r = (u + 0x7FFFu + ((u >> 16) & 1u)) >> 16;
    return (unsigned short)r;
}

// ---------------- logmap0 of embeddings -> t ----------------
__global__ void k_logmap(const float* __restrict__ eu, const float* __restrict__ ei,
                         int Nu, int Ntot, float* __restrict__ out) {
    int idx = blockIdx.x * blockDim.x + threadIdx.x;
    if (idx >= Ntot * 64) return;
    int n = idx >> 6, d = idx & 63;
    const float* src = (n < Nu) ? (eu + (size_t)n * 64) : (ei + (size_t)(n - Nu) * 64);
    float x0 = src[0];
    float alpha = fmaxf(x0, 1.0f + EPSF);
    float coef = acoshf(alpha) / sqrtf(fmaxf(alpha * alpha - 1.0f, EPSF));
    out[idx] = (d == 0) ? 0.0f : coef * src[d];
}

// ---------------- MoE ----------------
__global__ __launch_bounds__(256) void k_moe(
    const float* __restrict__ X, float* __restrict__ Y,
    const float* __restrict__ W, const float* __restrict__ Bb,
    const float* __restrict__ GW, const float* __restrict__ GB)
{
    __shared__ float sX[32][68];
    __shared__ float sG[32][8];
    const int tid = threadIdx.x;
    const int n0 = blockIdx.x * 32;

    for (int i = tid; i < 2048; i += 256)
        sX[i >> 6][i & 63] = X[(size_t)n0 * 64 + i];
    __syncthreads();

    {
        const int n = tid >> 3, e = tid & 7;
        float lg = GB[e];
        #pragma unroll 16
        for (int d = 0; d < 64; ++d) lg += sX[n][d] * GW[d * 8 + e];
        sG[n][e] = lg;
    }
    __syncthreads();
    if (tid < 32) {
        float mx = -1e30f;
        #pragma unroll
        for (int e = 0; e < 8; ++e) mx = fmaxf(mx, sG[tid][e]);
        float ex[8]; float s = 0.f;
        #pragma unroll
        for (int e = 0; e < 8; ++e) { ex[e] = expf(sG[tid][e] - mx); s += ex[e]; }
        float inv = 1.0f / s;
        #pragma unroll
        for (int e = 0; e < 8; ++e) sG[tid][e] = ex[e] * inv;
    }
    __syncthreads();

    const int o = tid & 63, nq = tid >> 6;
    float y[8][8];
    #pragma unroll
    for (int k = 0; k < 8; ++k)
        #pragma unroll
        for (int e = 0; e < 8; ++e) y[k][e] = 0.f;

    for (int dc = 0; dc < 16; ++dc) {
        float a[8][4];
        #pragma unroll
        for (int k = 0; k < 8; ++k) {
            float4 av = *(const float4*)(&sX[nq + 4 * k][dc * 4]);
            a[k][0] = av.x; a[k][1] = av.y; a[k][2] = av.z; a[k][3] = av.w;
        }
        #pragma unroll
        for (int e = 0; e < 8; ++e) {
            #pragma unroll
            for (int j = 0; j < 4; ++j) {
                const float w = W[(((size_t)e) << 12) + (size_t)(dc * 4 + j) * 64 + o];
                #pragma unroll
                for (int k = 0; k < 8; ++k) y[k][e] += a[k][j] * w;
            }
        }
    }

    #pragma unroll
    for (int k = 0; k < 8; ++k) {
        const int n = nq + 4 * k;
        float acc = 0.f;
        #pragma unroll
        for (int e = 0; e < 8; ++e) acc += sG[n][e] * (y[k][e] + Bb[e * 64 + o]);
        Y[(size_t)(n0 + n) * 64 + o] = acc;
    }
}

// ---------------- VAE mid ----------------
__global__ __launch_bounds__(256) void k_vae(
    const float* __restrict__ M, float* __restrict__ Hout,
    const float* __restrict__ EPSN,
    const float* __restrict__ muW, const float* __restrict__ mub,
    const float* __restrict__ lvW, const float* __restrict__ lvb,
    float* __restrict__ klslot)
{
    __shared__ float sM[32][68];
    __shared__ float sC[32];
    const int tid = threadIdx.x;
    const int n0 = blockIdx.x * 32;

    for (int i = tid; i < 2048; i += 256)
        sM[i >> 6][i & 63] = M[(size_t)n0 * 64 + i];
    __syncthreads();

    const int o = tid & 63, nq = tid >> 6;
    float ymu[8], ylv[8];
    #pragma unroll
    for (int k = 0; k < 8; ++k) { ymu[k] = 0.f; ylv[k] = 0.f; }

    for (int dc = 0; dc < 16; ++dc) {
        float a[8][4];
        #pragma unroll
        for (int k = 0; k < 8; ++k) {
            float4 av = *(const float4*)(&sM[nq + 4 * k][dc * 4]);
            a[k][0] = av.x; a[k][1] = av.y; a[k][2] = av.z; a[k][3] = av.w;
        }
        #pragma unroll
        for (int j = 0; j < 4; ++j) {
            const float wm = muW[(size_t)(dc * 4 + j) * 64 + o];
            const float wl = lvW[(size_t)(dc * 4 + j) * 64 + o];
            #pragma unroll
            for (int k = 0; k < 8; ++k) { ymu[k] += a[k][j] * wm; ylv[k] += a[k][j] * wl; }
        }
    }

    float u[8];
    float klp = 0.f;
    #pragma unroll
    for (int k = 0; k < 8; ++k) {
        const int n = nq + 4 * k;
        const float mu = ymu[k] + mub[o];
        const float lv = ylv[k] + lvb[o];
        const float elv = expf(lv);
        klp += 1.0f + lv - mu * mu - elv;
        u[k] = mu + EPSN[(size_t)(n0 + n) * 64 + o] * expf(0.5f * lv);
    }
    klp = wsum(klp);
    if ((tid & 63) == 0) atomicAdd(&klslot[(blockIdx.x * 4 + nq) & 255], klp);

    __syncthreads();
    #pragma unroll
    for (int k = 0; k < 8; ++k) sM[nq + 4 * k][o] = u[k];
    __syncthreads();

    if (tid < 32) {
        float ss = 0.f;
        for (int d = 1; d < 64; ++d) ss += sM[tid][d] * sM[tid][d];
        const float nr = fmaxf(sqrtf(ss), EPSF);
        const float r = sinhf(nr) / nr;
        const float sn = r * sqrtf(ss);
        const float scale = fminf(1.0f, MAXNRM / fmaxf(sn, EPSF));
        const float mult = r * scale;
        const float s2 = mult * mult * ss;
        const float z0 = sqrtf(1.0f + s2);
        const float alpha = fmaxf(z0, 1.0f + EPSF);
        const float coef = acoshf(alpha) / sqrtf(fmaxf(alpha * alpha - 1.0f, EPSF));
        sC[tid] = coef * mult;
    }
    __syncthreads();

    #pragma unroll
    for (int k = 0; k < 8; ++k) {
        const int n = nq + 4 * k;
        Hout[(size_t)(n0 + n) * 64 + o] = (o == 0) ? 0.f : sC[n] * sM[n][o];
    }
}

// ---------------- FFN ----------------
__global__ __launch_bounds__(256) void k_ffn(
    float* __restrict__ Hio,
    const float* __restrict__ f1W, const float* __restrict__ f1b,
    const float* __restrict__ f2W, const float* __restrict__ f2b)
{
    __shared__ float sH[32][68];
    __shared__ float sH1[32][132];
    const int tid = threadIdx.x;
    const int n0 = blockIdx.x * 32;

    for (int i = tid; i < 2048; i += 256)
        sH[i >> 6][i & 63] = Hio[(size_t)n0 * 64 + i];
    __syncthreads();

    const int o = tid & 63, nq = tid >> 6;
    float y0[8], y1[8];
    #pragma unroll
    for (int k = 0; k < 8; ++k) { y0[k] = 0.f; y1[k] = 0.f; }

    for (int dc = 0; dc < 16; ++dc) {
        float a[8][4];
        #pragma unroll
        for (int k = 0; k < 8; ++k) {
            float4 av = *(const float4*)(&sH[nq + 4 * k][dc * 4]);
            a[k][0] = av.x; a[k][1] = av.y; a[k][2] = av.z; a[k][3] = av.w;
        }
        #pragma unroll
        for (int j = 0; j < 4; ++j) {
            const float w0 = f1W[(size_t)(dc * 4 + j) * 128 + o];
            const float w1 = f1W[(size_t)(dc * 4 + j) * 128 + 64 + o];
            #pragma unroll
            for (int k = 0; k < 8; ++k) { y0[k] += a[k][j] * w0; y1[k] += a[k][j] * w1; }
        }
    }
    #pragma unroll
    for (int k = 0; k < 8; ++k) {
        const int n = nq + 4 * k;
        sH1[n][o] = fmaxf(y0[k] + f1b[o], 0.f);
        sH1[n][64 + o] = fmaxf(y1[k] + f1b[64 + o], 0.f);
    }
    __syncthreads();

    float y2[8];
    #pragma unroll
    for (int k = 0; k < 8; ++k) y2[k] = 0.f;
    for (int dc = 0; dc < 32; ++dc) {
        float a[8][4];
        #pragma unroll
        for (int k = 0; k < 8; ++k) {
            float4 av = *(const float4*)(&sH1[nq + 4 * k][dc * 4]);
            a[k][0] = av.x; a[k][1] = av.y; a[k][2] = av.z; a[k][3] = av.w;
        }
        #pragma unroll
        for (int j = 0; j < 4; ++j) {
            const float w = f2W[(size_t)(dc * 4 + j) * 64 + o];
            #pragma unroll
            for (int k = 0; k < 8; ++k) y2[k] += a[k][j] * w;
        }
    }
    #pragma unroll
    for (int k = 0; k < 8; ++k)
        Hio[(size_t)(n0 + nq + 4 * k) * 64 + o] = y2[k] + f2b[o];
}

// ---------------- recon loss ----------------
__global__ void k_recon(const float* __restrict__ HM, const float* __restrict__ M,
                        int Ntot, float* __restrict__ slot)
{
    const int w = threadIdx.x >> 6, d = threadIdx.x & 63;
    const int n = blockIdx.x * 4 + w;
    if (n >= Ntot) return;
    const float hv = HM[(size_t)n * 64 + d];
    const float mv = M[(size_t)n * 64 + d];
    const float ssh = wsum(d == 0 ? 0.f : hv * hv);
    const float ssm = wsum(d == 0 ? 0.f : mv * mv);

    const float nm = fmaxf(sqrtf(ssm), EPSF);
    const float rm = sinhf(nm) / nm;
    const float em = (d == 0) ? coshf(nm) : rm * mv;

    const float nh = fmaxf(sqrtf(ssh), EPSF);
    const float rh = sinhf(nh) / nh;
    const float sn = rh * sqrtf(ssh);
    const float scale = fminf(1.0f, MAXNRM / fmaxf(sn, EPSF));
    const float mult = rh * scale;
    const float rec = (d == 0) ? sqrtf(1.0f + mult * mult * ssh) : mult * hv;

    const float inner = wsum(d == 0 ? -rec * em : rec * em);
    if (d == 0) {
        const float dd = acoshf(fmaxf(-inner, 1.0f + EPSF));
        atomicAdd(&slot[(blockIdx.x * 4 + w) & 255], dd * dd);
    }
}

// ---------------- fused exact row count + bucket histogram ----------------
__global__ __launch_bounds__(256) void k_count(const int* __restrict__ rows, int nnz,
                                               int* __restrict__ cnt, int* __restrict__ bhist) {
    __shared__ int h[NB];
    for (int j = threadIdx.x; j < NB; j += 256) h[j] = 0;
    __syncthreads();
    for (int i = blockIdx.x * 256 + threadIdx.x; i < nnz; i += gridDim.x * 256) {
        const int r = rows[i];
        atomicAdd(&cnt[r], 1);
        atomicAdd(&h[r >> 7], 1);
    }
    __syncthreads();
    for (int j = threadIdx.x; j < NB; j += 256)
        if (h[j]) atomicAdd(&bhist[j], h[j]);
}

// ---------------- exact row scan (F = row starts) ----------------
__global__ __launch_bounds__(1024) void k_scan1(const int* __restrict__ cnt, int n,
                                                int* __restrict__ F, int* __restrict__ bsum) {
    __shared__ int s[1024];
    const int tid = threadIdx.x;
    const int i = blockIdx.x * 1024 + tid;
    int v = (i < n) ? cnt[i] : 0;
    s[tid] = v;
    __syncthreads();
    for (int off = 1; off < 1024; off <<= 1) {
        int t = (tid >= off) ? s[tid - off] : 0;
        __syncthreads();
        s[tid] += t;
        __syncthreads();
    }
    if (i < n) F[i] = s[tid] - v;
    if (tid == 1023) bsum[blockIdx.x] = s[tid];
}

__global__ void k_scan2(int* __restrict__ bsum, int nb, int* __restrict__ F, int Ntot, int nnz) {
    if (threadIdx.x == 0 && blockIdx.x == 0) {
        int run = 0;
        for (int b = 0; b < nb; ++b) { int t = bsum[b]; bsum[b] = run; run += t; }
        F[Ntot] = nnz;
    }
}

__global__ __launch_bounds__(1024) void k_scan3(int* __restrict__ F, const int* __restrict__ bsum, int n) {
    int i = blockIdx.x * 1024 + threadIdx.x;
    if (i < n) F[i] += bsum[blockIdx.x];
}

// ---------------- bucket scan (1 block) ----------------
__global__ __launch_bounds__(1024) void k_bscan(const int* __restrict__ bhist,
                                                int* __restrict__ bstart, int* __restrict__ gcur) {
    __shared__ int s[1024];
    const int tid = threadIdx.x;
    int v = (tid < NB) ? bhist[tid] : 0;
    s[tid] = v;
    __syncthreads();
    for (int off = 1; off < 1024; off <<= 1) {
        int t = (tid >= off) ? s[tid - off] : 0;
        __syncthreads();
        s[tid] += t;
        __syncthreads();
    }
    if (tid < NB) {
        bstart[tid + 1] = s[tid];
        gcur[tid] = s[tid] - v;
        if (tid == 0) bstart[0] = 0;
    }
}

// ---------------- stage-1 bucket scatter, LDS-aggregated cursors ----------------
__global__ __launch_bounds__(256) void k_bscatter(
    const int* __restrict__ rows, const int* __restrict__ cols,
    const float* __restrict__ vals, int nnz,
    int* __restrict__ gcur, int2* __restrict__ tmp)
{
    __shared__ int lh[NB];
    __shared__ int lb[NB];
    const int tid = threadIdx.x;
    for (int j = tid; j < NB; j += 256) lh[j] = 0;
    __syncthreads();

    const int base = blockIdx.x * (256 * EPT);
    int r[EPT], c[EPT], lp[EPT];
    float v[EPT];
    #pragma unroll
    for (int j = 0; j < EPT; ++j) {
        const int i = base + j * 256 + tid;
        if (i < nnz) {
            r[j] = rows[i]; c[j] = cols[i]; v[j] = vals[i];
            lp[j] = atomicAdd(&lh[r[j] >> 7], 1);
        }
    }
    __syncthreads();
    for (int j = tid; j < NB; j += 256)
        if (lh[j]) lb[j] = atomicAdd(&gcur[j], lh[j]);
    __syncthreads();
    #pragma unroll
    for (int j = 0; j < EPT; ++j) {
        const int i = base + j * 256 + tid;
        if (i < nnz) {
            int2 e;
            e.x = ((r[j] & 127) << 17) | c[j];
            e.y = __float_as_int(v[j]);
            tmp[lb[r[j] >> 7] + lp[j]] = e;
        }
    }
}

// ---------------- stage-2: exact CSR placement, LDS row cursors only ----------------
__global__ __launch_bounds__(256) void k_sort(
    const int2* __restrict__ tmp, const int* __restrict__ bstart,
    const int* __restrict__ F, int2* __restrict__ sedge)
{
    __shared__ int cnt[RPB];
    const int b = blockIdx.x;
    if (threadIdx.x < RPB) cnt[threadIdx.x] = 0;
    __syncthreads();
    const int s = bstart[b], t = bstart[b + 1];
    for (int i = s + threadIdx.x; i < t; i += 256) {
        const int2 e = tmp[i];
        const int rib = ((unsigned)e.x) >> 17;
        const int col = e.x & 0x1FFFF;
        const int lpos = atomicAdd(&cnt[rib], 1);
        const int row = (b << 7) + rib;
        int2 o; o.x = col; o.y = e.y;
        sedge[F[row] + lpos] = o;
    }
}

// ---------------- fp32 -> bf16 table copy ----------------
__global__ void k_tobf16(const float* __restrict__ in, unsigned short* __restrict__ out, int n8) {
    const int i = blockIdx.x * 256 + threadIdx.x;
    if (i >= n8) return;
    const float4 a = ((const float4*)in)[2 * i];
    const float4 b = ((const float4*)in)[2 * i + 1];
    uint4 p;
    p.x = (unsigned)f2bf(a.x) | ((unsigned)f2bf(a.y) << 16);
    p.y = (unsigned)f2bf(a.z) | ((unsigned)f2bf(a.w) << 16);
    p.z = (unsigned)f2bf(b.x) | ((unsigned)f2bf(b.y) << 16);
    p.w = (unsigned)f2bf(b.z) | ((unsigned)f2bf(b.w) << 16);
    ((uint4*)out)[i] = p;
}

// ---------------- SpMM: row per wave, bf16 gather, fp32 accumulate ----------------
template <int MODE>
__global__ __launch_bounds__(256) void k_spmm(
    const unsigned short* __restrict__ in, unsigned short* __restrict__ outb,
    float* __restrict__ osum,
    const int* __restrict__ F, const int2* __restrict__ sedge, int Ntot)
{
    const int r = blockIdx.x * 4 + (threadIdx.x >> 6);
    if (r >= Ntot) return;
    const int lane = threadIdx.x & 63;
    const int g = lane >> 3, q = lane & 7;
    const int e0 = F[r], e1 = F[r + 1];

    float acc0[8], acc1[8];
    #pragma unroll
    for (int j = 0; j < 8; ++j) { acc0[j] = 0.f; acc1[j] = 0.f; }

    for (int base = e0; base < e1; base += 16) {
        const int ea = base + g, eb = base + 8 + g;
        if (ea < e1) {
            const int2 ed = sedge[ea];
            const float v = __int_as_float(ed.y);
            const uint4 hb = *(const uint4*)(in + (((size_t)ed.x) << 6) + q * 8);
            acc0[0] += v * __uint_as_float(hb.x << 16);
            acc0[1] += v * __uint_as_float(hb.x & 0xFFFF0000u);
            acc0[2] += v * __uint_as_float(hb.y << 16);
            acc0[3] += v * __uint_as_float(hb.y & 0xFFFF0000u);
            acc0[4] += v * __uint_as_float(hb.z << 16);
            acc0[5] += v * __uint_as_float(hb.z & 0xFFFF0000u);
            acc0[6] += v * __uint_as_float(hb.w << 16);
            acc0[7] += v * __uint_as_float(hb.w & 0xFFFF0000u);
        }
        if (eb < e1) {
            const int2 ed = sedge[eb];
            const float v = __int_as_float(ed.y);
            const uint4 hb = *(const uint4*)(in + (((size_t)ed.x) << 6) + q * 8);
            acc1[0] += v * __uint_as_float(hb.x << 16);
            acc1[1] += v * __uint_as_float(hb.x & 0xFFFF0000u);
            acc1[2] += v * __uint_as_float(hb.y << 16);
            acc1[3] += v * __uint_as_float(hb.y & 0xFFFF0000u);
            acc1[4] += v * __uint_as_float(hb.z << 16);
            acc1[5] += v * __uint_as_float(hb.z & 0xFFFF0000u);
            acc1[6] += v * __uint_as_float(hb.w << 16);
            acc1[7] += v * __uint_as_float(hb.w & 0xFFFF0000u);
        }
    }
    #pragma unroll
    for (int j = 0; j < 8; ++j) acc0[j] += acc1[j];

    #pragma unroll
    for (int off = 8; off < 64; off <<= 1)
        #pragma unroll
        for (int j = 0; j < 8; ++j) acc0[j] += __shfl_xor(acc0[j], off, 64);

    if (g == 0) {
        const size_t ob = (((size_t)r) << 6) + q * 8;
        uint4 p;
        p.x = (unsigned)f2bf(acc0[0]) | ((unsigned)f2bf(acc0[1]) << 16);
        p.y = (unsigned)f2bf(acc0[2]) | ((unsigned)f2bf(acc0[3]) << 16);
        p.z = (unsigned)f2bf(acc0[4]) | ((unsigned)f2bf(acc0[5]) << 16);
        p.w = (unsigned)f2bf(acc0[6]) | ((unsigned)f2bf(acc0[7]) << 16);
        *(uint4*)(outb + ob) = p;

        float4 lo = make_float4(acc0[0], acc0[1], acc0[2], acc0[3]);
        float4 hi = make_float4(acc0[4], acc0[5], acc0[6], acc0[7]);
        if (MODE == 0) {
            *(float4*)(osum + ob) = lo;
            *(float4*)(osum + ob + 4) = hi;
        } else {
            float4 a = *(const float4*)(osum + ob);
            float4 b = *(const float4*)(osum + ob + 4);
            a.x += lo.x; a.y += lo.y; a.z += lo.z; a.w += lo.w;
            b.x += hi.x; b.y += hi.y; b.z += hi.z; b.w += hi.w;
            *(float4*)(osum + ob) = a;
            *(float4*)(osum + ob + 4) = b;
        }
    }
}

// ---------------- expmap0(out_sum, project=True) ----------------
__global__ void k_expmap_proj(const float* __restrict__ in, float* __restrict__ out, int Ntot) {
    const int w = threadIdx.x >> 6, d = threadIdx.x & 63;
    const int n = blockIdx.x * 4 + w;
    if (n >= Ntot) return;
    const float v = in[((size_t)n << 6) + d];
    const float ss = wsum(d == 0 ? 0.f : v * v);
    const float nr = fmaxf(sqrtf(ss), EPSF);
    const float r = sinhf(nr) / nr;
    const float sn = r * sqrtf(ss);
    const float scale = fminf(1.0f, MAXNRM / fmaxf(sn, EPSF));
    const float mult = r * scale;
    out[((size_t)n << 6) + d] = (d == 0) ? sqrtf(1.0f + mult * mult * ss) : mult * v;
}

// ---------------- triple margin loss ----------------
__global__ __launch_bounds__(256) void k_triples(
    const float* __restrict__ O, const int* __restrict__ tri,
    int T, float* __restrict__ slot)
{
    const int lane = threadIdx.x & 63;
    const int g = lane >> 4, q = lane & 15;
    const int wid = blockIdx.x * 4 + (threadIdx.x >> 6);
    const int nwaves = gridDim.x * 4;

    float racc = 0.f;
    for (int tb = wid * 4; tb < T; tb += nwaves * 4) {
        const int t = tb + g;
        const int a = tri[3 * t], p = tri[3 * t + 1], nn = tri[3 * t + 2];
        const float4 av = *(const float4*)(O + (((size_t)a) << 6) + q * 4);
        const float4 pv = *(const float4*)(O + (((size_t)p) << 6) + q * 4);
        const float4 nv = *(const float4*)(O + (((size_t)nn) << 6) + q * 4);
        const float s0 = (q == 0) ? -1.f : 1.f;
        float i1 = s0 * av.x * pv.x + av.y * pv.y + av.z * pv.z + av.w * pv.w;
        float i2 = s0 * av.x * nv.x + av.y * nv.y + av.z * nv.z + av.w * nv.w;
        #pragma unroll
        for (int off = 1; off < 16; off <<= 1) {
            i1 += __shfl_xor(i1, off, 64);
            i2 += __shfl_xor(i2, off, 64);
        }
        if (q == 0) {
            const float d1 = acoshf(fmaxf(-i1, 1.0f + EPSF));
            const float d2 = acoshf(fmaxf(-i2, 1.0f + EPSF));
            const float l = d1 * d1 - d2 * d2 + 0.1f;
            if (l > 0.f) racc += l;
        }
    }

    racc = wsum(racc);
    __shared__ float sb[4];
    if (lane == 0) sb[threadIdx.x >> 6] = racc;
    __syncthreads();
    if (threadIdx.x == 0)
        atomicAdd(&slot[blockIdx.x & 255], sb[0] + sb[1] + sb[2] + sb[3]);
}

// ---------------- finalize ----------------
__global__ void k_final(const float* __restrict__ slots, float* __restrict__ out, int Ntot)
{
    const int tid = threadIdx.x;
    float m = slots[tid], r = slots[256 + tid], k = slots[512 + tid];
    m = wsum(m); r = wsum(r); k = wsum(k);
    __shared__ float sm[4], sr[4], sk[4];
    if ((tid & 63) == 0) { sm[tid >> 6] = m; sr[tid >> 6] = r; sk[tid >> 6] = k; }
    __syncthreads();
    if (tid == 0) {
        const float M = sm[0] + sm[1] + sm[2] + sm[3];
        const float R = sr[0] + sr[1] + sr[2] + sr[3];
        const float K = sk[0] + sk[1] + sk[2] + sk[3];
        const float recon = R / (float)Ntot;
        const float kl = -0.5f * K / ((float)Ntot * 64.0f);
        out[0] = M + 0.1f * (recon + kl);
    }
}

extern "C" void kernel_launch(void* const* d_in, const int* in_sizes, int n_in,
                              void* d_out, int out_size, void* d_ws, size_t ws_size,
                              hipStream_t stream)
{
    const float* emb_user = (const float*)d_in[0];
    const float* emb_item = (const float*)d_in[1];
    const int*   adj_rows = (const int*)d_in[2];
    const int*   adj_cols = (const int*)d_in[3];
    const float* adj_vals = (const float*)d_in[4];
    const int*   triples  = (const int*)d_in[5];
    const float* epsin    = (const float*)d_in[6];
    const float* tW  = (const float*)d_in[7];
    const float* tb  = (const float*)d_in[8];
    const float* tgW = (const float*)d_in[9];
    const float* tgb = (const float*)d_in[10];
    const float* muW = (const float*)d_in[11];
    const float* mub = (const float*)d_in[12];
    const float* lvW = (const float*)d_in[13];
    const float* lvb = (const float*)d_in[14];
    const float* f1W = (const float*)d_in[15];
    const float* f1b = (const float*)d_in[16];
    const float* f2W = (const float*)d_in[17];
    const float* f2b = (const float*)d_in[18];
    const float* dW  = (const float*)d_in[19];
    const float* db  = (const float*)d_in[20];
    const float* dgW = (const float*)d_in[21];
    const float* dgb = (const float*)d_in[22];

    const int Nu = in_sizes[0] / 64, Ni = in_sizes[1] / 64;
    const int N = Nu + Ni;            // 100000
    const int NNZ = in_sizes[4];      // 3200000
    const int T = in_sizes[5] / 3;    // 262144

    float* ws = (float*)d_ws;
    size_t off = 0;
    float* slots = ws + off; off += 1024;            // margin / recon / kl slots
    float* A  = ws + off; off += (size_t)N * 64;     // t/h ; then stage-1 tmp edges; then bf16 {Bh, Hb1}
    float* B  = ws + off; off += (size_t)N * 64;     // m ; then O (expmap output)
    float* C  = ws + off; off += (size_t)N * 64;     // hm ; then out_sum (fp32)
    float* D  = ws + off; off += (size_t)N * 64;     // sedge (exact CSR int2[NNZ])
    float* Hb2f = ws + off; off += (size_t)N * 32;   // bf16 pong buffer
    int*   F  = (int*)(ws + off); off += (size_t)N + 64;   // row starts
    int*   Gc = (int*)(ws + off); off += (size_t)N;        // exact row counts
    int*   bsum   = (int*)(ws + off); off += 1024;
    int*   bstart = (int*)(ws + off); off += 1024;
    int*   bhist  = (int*)(ws + off); off += 1024;
    int*   gcur   = (int*)(ws + off); off += 1024;

    int2* tmp   = (int2*)A;                         // stage-1 bucketed edges (25.6 MB)
    int2* sedge = (int2*)D;                         // exact CSR edges (25.6 MB)
    unsigned short* Bh  = (unsigned short*)A;                         // bf16(m), after k_sort
    unsigned short* Hb1 = (unsigned short*)A + (size_t)N * 64;        // bf16 ping
    unsigned short* Hb2 = (unsigned short*)Hb2f;                      // bf16 pong

    hipMemsetAsync(slots, 0, 1024 * sizeof(float), stream);
    hipMemsetAsync(bhist, 0, 1024 * sizeof(int), stream);
    hipMemsetAsync(Gc, 0, (size_t)N * sizeof(int), stream);

    const int nb32 = N / 32;          // 3125
    const int nbN4 = (N + 3) / 4;     // 25000

    // dense chain
    k_logmap<<<(N * 64 + 255) / 256, 256, 0, stream>>>(emb_user, emb_item, Nu, N, A);
    k_moe<<<nb32, 256, 0, stream>>>(A, B, tW, tb, tgW, tgb);
    k_vae<<<nb32, 256, 0, stream>>>(B, A, epsin, muW, mub, lvW, lvb, slots + 512);
    k_ffn<<<nb32, 256, 0, stream>>>(A, f1W, f1b, f2W, f2b);
    k_moe<<<nb32, 256, 0, stream>>>(A, C, dW, db, dgW, dgb);
    k_recon<<<nbN4, 256, 0, stream>>>(C, B, N, slots + 256);

    // CSR build
    k_count<<<1024, 256, 0, stream>>>(adj_rows, NNZ, Gc, bhist);
    const int nsb = (N + 1023) / 1024;   // 98
    k_scan1<<<nsb, 1024, 0, stream>>>(Gc, N, F, bsum);
    k_scan2<<<1, 64, 0, stream>>>(bsum, nsb, F, N, NNZ);
    k_scan3<<<nsb, 1024, 0, stream>>>(F, bsum, N);
    k_bscan<<<1, 1024, 0, stream>>>(bhist, bstart, gcur);
    const int ns1 = (NNZ + 256 * EPT - 1) / (256 * EPT);   // 782
    k_bscatter<<<ns1, 256, 0, stream>>>(adj_rows, adj_cols, adj_vals, NNZ, gcur, tmp);
    k_sort<<<NB, 256, 0, stream>>>(tmp, bstart, F, sedge);

    // bf16 table for layer-1 gather (A's tmp is dead after k_sort)
    k_tobf16<<<(N * 64 / 8 + 255) / 256, 256, 0, stream>>>(B, Bh, N * 8);

    // 3-layer spmm chain, bf16 gather + fp32 out_sum in C
    k_spmm<0><<<nbN4, 256, 0, stream>>>(Bh,  Hb1, C, F, sedge, N);
    k_spmm<1><<<nbN4, 256, 0, stream>>>(Hb1, Hb2, C, F, sedge, N);
    k_spmm<1><<<nbN4, 256, 0, stream>>>(Hb2, Bh,  C, F, sedge, N);

    k_expmap_proj<<<nbN4, 256, 0, stream>>>(C, B, N);
    k_triples<<<2048, 256, 0, stream>>>(B, triples, T, slots);
    k_final<<<1, 256, 0, stream>>>(slots, (float*)d_out, N);
}

// Round 5
// 878.816 us; speedup vs baseline: 6.1476x; 1.1845x over previous
//
#include <hip/hip_runtime.h>
#include <math.h>

#define EPSF 1e-7f
#define MAXNRM 10.0f
#define NB 782          // ceil(100000/128) buckets
#define RPB 128         // rows per bucket
#define EPT 16          // edges per thread in stage-1 scatter

__device__ __forceinline__ float wsum(float v) {
    #pragma unroll
    for (int off = 32; off > 0; off >>= 1) v += __shfl_xor(v, off, 64);
    return v;
}

__device__ __forceinline__ unsigned short f2bf(float x) {   // RNE
    unsigned u = __float_as_uint(x);
    unsigned r = (u + 0x7FFFu + ((u >> 16) & 1u)) >> 16;
    return (unsigned short)r;
}

// ---------------- logmap0 of embeddings -> t (16 lanes/row, float4) ----------------
__global__ __launch_bounds__(256) void k_logmap(const float* __restrict__ eu, const float* __restrict__ ei,
                                                int Nu, int Ntot, float* __restrict__ out) {
    const int lane = threadIdx.x & 63;
    const int g = lane >> 4, q = lane & 15;
    const int n = blockIdx.x * 16 + (threadIdx.x >> 6) * 4 + g;
    if (n >= Ntot) return;
    const float* src = (n < Nu) ? (eu + (size_t)n * 64) : (ei + (size_t)(n - Nu) * 64);
    const float x0 = src[0];
    const float alpha = fmaxf(x0, 1.0f + EPSF);
    const float coef = acoshf(alpha) / sqrtf(fmaxf(alpha * alpha - 1.0f, EPSF));
    const float4 v = *(const float4*)(src + q * 4);
    float4 o;
    o.x = (q == 0) ? 0.0f : coef * v.x;
    o.y = coef * v.y; o.z = coef * v.z; o.w = coef * v.w;
    *(float4*)(out + ((size_t)n << 6) + q * 4) = o;
}

// ---------------- MoE ----------------
__global__ __launch_bounds__(256) void k_moe(
    const float* __restrict__ X, float* __restrict__ Y,
    const float* __restrict__ W, const float* __restrict__ Bb,
    const float* __restrict__ GW, const float* __restrict__ GB)
{
    __shared__ float sX[32][68];
    __shared__ float sG[32][8];
    const int tid = threadIdx.x;
    const int n0 = blockIdx.x * 32;

    for (int i = tid; i < 2048; i += 256)
        sX[i >> 6][i & 63] = X[(size_t)n0 * 64 + i];
    __syncthreads();

    {
        const int n = tid >> 3, e = tid & 7;
        float lg = GB[e];
        #pragma unroll 16
        for (int d = 0; d < 64; ++d) lg += sX[n][d] * GW[d * 8 + e];
        sG[n][e] = lg;
    }
    __syncthreads();
    if (tid < 32) {
        float mx = -1e30f;
        #pragma unroll
        for (int e = 0; e < 8; ++e) mx = fmaxf(mx, sG[tid][e]);
        float ex[8]; float s = 0.f;
        #pragma unroll
        for (int e = 0; e < 8; ++e) { ex[e] = expf(sG[tid][e] - mx); s += ex[e]; }
        float inv = 1.0f / s;
        #pragma unroll
        for (int e = 0; e < 8; ++e) sG[tid][e] = ex[e] * inv;
    }
    __syncthreads();

    const int o = tid & 63, nq = tid >> 6;
    float y[8][8];
    #pragma unroll
    for (int k = 0; k < 8; ++k)
        #pragma unroll
        for (int e = 0; e < 8; ++e) y[k][e] = 0.f;

    for (int dc = 0; dc < 16; ++dc) {
        float a[8][4];
        #pragma unroll
        for (int k = 0; k < 8; ++k) {
            float4 av = *(const float4*)(&sX[nq + 4 * k][dc * 4]);
            a[k][0] = av.x; a[k][1] = av.y; a[k][2] = av.z; a[k][3] = av.w;
        }
        #pragma unroll
        for (int e = 0; e < 8; ++e) {
            #pragma unroll
            for (int j = 0; j < 4; ++j) {
                const float w = W[(((size_t)e) << 12) + (size_t)(dc * 4 + j) * 64 + o];
                #pragma unroll
                for (int k = 0; k < 8; ++k) y[k][e] += a[k][j] * w;
            }
        }
    }

    #pragma unroll
    for (int k = 0; k < 8; ++k) {
        const int n = nq + 4 * k;
        float acc = 0.f;
        #pragma unroll
        for (int e = 0; e < 8; ++e) acc += sG[n][e] * (y[k][e] + Bb[e * 64 + o]);
        Y[(size_t)(n0 + n) * 64 + o] = acc;
    }
}

// ---------------- VAE mid ----------------
__global__ __launch_bounds__(256) void k_vae(
    const float* __restrict__ M, float* __restrict__ Hout,
    const float* __restrict__ EPSN,
    const float* __restrict__ muW, const float* __restrict__ mub,
    const float* __restrict__ lvW, const float* __restrict__ lvb,
    float* __restrict__ klslot)
{
    __shared__ float sM[32][68];
    __shared__ float sC[32];
    const int tid = threadIdx.x;
    const int n0 = blockIdx.x * 32;

    for (int i = tid; i < 2048; i += 256)
        sM[i >> 6][i & 63] = M[(size_t)n0 * 64 + i];
    __syncthreads();

    const int o = tid & 63, nq = tid >> 6;
    float ymu[8], ylv[8];
    #pragma unroll
    for (int k = 0; k < 8; ++k) { ymu[k] = 0.f; ylv[k] = 0.f; }

    for (int dc = 0; dc < 16; ++dc) {
        float a[8][4];
        #pragma unroll
        for (int k = 0; k < 8; ++k) {
            float4 av = *(const float4*)(&sM[nq + 4 * k][dc * 4]);
            a[k][0] = av.x; a[k][1] = av.y; a[k][2] = av.z; a[k][3] = av.w;
        }
        #pragma unroll
        for (int j = 0; j < 4; ++j) {
            const float wm = muW[(size_t)(dc * 4 + j) * 64 + o];
            const float wl = lvW[(size_t)(dc * 4 + j) * 64 + o];
            #pragma unroll
            for (int k = 0; k < 8; ++k) { ymu[k] += a[k][j] * wm; ylv[k] += a[k][j] * wl; }
        }
    }

    float u[8];
    float klp = 0.f;
    #pragma unroll
    for (int k = 0; k < 8; ++k) {
        const int n = nq + 4 * k;
        const float mu = ymu[k] + mub[o];
        const float lv = ylv[k] + lvb[o];
        const float elv = expf(lv);
        klp += 1.0f + lv - mu * mu - elv;
        u[k] = mu + EPSN[(size_t)(n0 + n) * 64 + o] * expf(0.5f * lv);
    }
    klp = wsum(klp);
    if ((tid & 63) == 0) atomicAdd(&klslot[(blockIdx.x * 4 + nq) & 255], klp);

    __syncthreads();
    #pragma unroll
    for (int k = 0; k < 8; ++k) sM[nq + 4 * k][o] = u[k];
    __syncthreads();

    {   // per-row norm: 8 lanes per row (32 rows x 8 lanes = 256 threads)
        const int r2 = tid >> 3, j = tid & 7;
        const float4 a = *(const float4*)(&sM[r2][j * 8]);
        const float4 b = *(const float4*)(&sM[r2][j * 8 + 4]);
        const float ax = (j == 0) ? 0.f : a.x;
        float ss = ax * ax + a.y * a.y + a.z * a.z + a.w * a.w
                 + b.x * b.x + b.y * b.y + b.z * b.z + b.w * b.w;
        #pragma unroll
        for (int off = 1; off < 8; off <<= 1) ss += __shfl_xor(ss, off, 64);
        if (j == 0) {
            const float nr = fmaxf(sqrtf(ss), EPSF);
            const float r = sinhf(nr) / nr;
            const float sn = r * sqrtf(ss);
            const float scale = fminf(1.0f, MAXNRM / fmaxf(sn, EPSF));
            const float mult = r * scale;
            const float s2 = mult * mult * ss;
            const float z0 = sqrtf(1.0f + s2);
            const float alpha = fmaxf(z0, 1.0f + EPSF);
            const float coef = acoshf(alpha) / sqrtf(fmaxf(alpha * alpha - 1.0f, EPSF));
            sC[r2] = coef * mult;
        }
    }
    __syncthreads();

    #pragma unroll
    for (int k = 0; k < 8; ++k) {
        const int n = nq + 4 * k;
        Hout[(size_t)(n0 + n) * 64 + o] = (o == 0) ? 0.f : sC[n] * sM[n][o];
    }
}

// ---------------- FFN ----------------
__global__ __launch_bounds__(256) void k_ffn(
    float* __restrict__ Hio,
    const float* __restrict__ f1W, const float* __restrict__ f1b,
    const float* __restrict__ f2W, const float* __restrict__ f2b)
{
    __shared__ float sH[32][68];
    __shared__ float sH1[32][132];
    const int tid = threadIdx.x;
    const int n0 = blockIdx.x * 32;

    for (int i = tid; i < 2048; i += 256)
        sH[i >> 6][i & 63] = Hio[(size_t)n0 * 64 + i];
    __syncthreads();

    const int o = tid & 63, nq = tid >> 6;
    float y0[8], y1[8];
    #pragma unroll
    for (int k = 0; k < 8; ++k) { y0[k] = 0.f; y1[k] = 0.f; }

    for (int dc = 0; dc < 16; ++dc) {
        float a[8][4];
        #pragma unroll
        for (int k = 0; k < 8; ++k) {
            float4 av = *(const float4*)(&sH[nq + 4 * k][dc * 4]);
            a[k][0] = av.x; a[k][1] = av.y; a[k][2] = av.z; a[k][3] = av.w;
        }
        #pragma unroll
        for (int j = 0; j < 4; ++j) {
            const float w0 = f1W[(size_t)(dc * 4 + j) * 128 + o];
            const float w1 = f1W[(size_t)(dc * 4 + j) * 128 + 64 + o];
            #pragma unroll
            for (int k = 0; k < 8; ++k) { y0[k] += a[k][j] * w0; y1[k] += a[k][j] * w1; }
        }
    }
    #pragma unroll
    for (int k = 0; k < 8; ++k) {
        const int n = nq + 4 * k;
        sH1[n][o] = fmaxf(y0[k] + f1b[o], 0.f);
        sH1[n][64 + o] = fmaxf(y1[k] + f1b[64 + o], 0.f);
    }
    __syncthreads();

    float y2[8];
    #pragma unroll
    for (int k = 0; k < 8; ++k) y2[k] = 0.f;
    for (int dc = 0; dc < 32; ++dc) {
        float a[8][4];
        #pragma unroll
        for (int k = 0; k < 8; ++k) {
            float4 av = *(const float4*)(&sH1[nq + 4 * k][dc * 4]);
            a[k][0] = av.x; a[k][1] = av.y; a[k][2] = av.z; a[k][3] = av.w;
        }
        #pragma unroll
        for (int j = 0; j < 4; ++j) {
            const float w = f2W[(size_t)(dc * 4 + j) * 64 + o];
            #pragma unroll
            for (int k = 0; k < 8; ++k) y2[k] += a[k][j] * w;
        }
    }
    #pragma unroll
    for (int k = 0; k < 8; ++k)
        Hio[(size_t)(n0 + nq + 4 * k) * 64 + o] = y2[k] + f2b[o];
}

// ---------------- recon loss: 16 lanes/node, dot-product identity ----------------
__global__ __launch_bounds__(256) void k_recon(
    const float* __restrict__ HM, const float* __restrict__ M,
    int Ntot, float* __restrict__ slot)
{
    const int lane = threadIdx.x & 63;
    const int g = lane >> 4, q = lane & 15;
    const int n = blockIdx.x * 16 + (threadIdx.x >> 6) * 4 + g;

    float ssh = 0.f, ssm = 0.f, dot = 0.f;
    if (n < Ntot) {
        const float4 h = *(const float4*)(HM + ((size_t)n << 6) + q * 4);
        const float4 m = *(const float4*)(M  + ((size_t)n << 6) + q * 4);
        const float hx = (q == 0) ? 0.f : h.x;
        const float mx = (q == 0) ? 0.f : m.x;
        ssh = hx * hx + h.y * h.y + h.z * h.z + h.w * h.w;
        ssm = mx * mx + m.y * m.y + m.z * m.z + m.w * m.w;
        dot = hx * mx + h.y * m.y + h.z * m.z + h.w * m.w;
    }
    #pragma unroll
    for (int off = 1; off < 16; off <<= 1) {
        ssh += __shfl_xor(ssh, off, 64);
        ssm += __shfl_xor(ssm, off, 64);
        dot += __shfl_xor(dot, off, 64);
    }

    float part = 0.f;
    if (q == 0 && n < Ntot) {
        const float nm = fmaxf(sqrtf(ssm), EPSF);
        const float em0 = coshf(nm);
        const float rm = sinhf(nm) / nm;

        const float nh = fmaxf(sqrtf(ssh), EPSF);
        const float rh = sinhf(nh) / nh;
        const float sn = rh * sqrtf(ssh);
        const float scale = fminf(1.0f, MAXNRM / fmaxf(sn, EPSF));
        const float mult = rh * scale;
        const float rec0 = sqrtf(1.0f + mult * mult * ssh);

        const float inner = mult * rm * dot - rec0 * em0;
        const float dd = acoshf(fmaxf(-inner, 1.0f + EPSF));
        part = dd * dd;
    }
    part = wsum(part);
    __shared__ float sb[4];
    if (lane == 0) sb[threadIdx.x >> 6] = part;
    __syncthreads();
    if (threadIdx.x == 0)
        atomicAdd(&slot[blockIdx.x & 255], sb[0] + sb[1] + sb[2] + sb[3]);
}

// ---------------- fused exact row count + bucket histogram ----------------
__global__ __launch_bounds__(256) void k_count(const int* __restrict__ rows, int nnz,
                                               int* __restrict__ cnt, int* __restrict__ bhist) {
    __shared__ int h[NB];
    for (int j = threadIdx.x; j < NB; j += 256) h[j] = 0;
    __syncthreads();
    for (int i = blockIdx.x * 256 + threadIdx.x; i < nnz; i += gridDim.x * 256) {
        const int r = rows[i];
        atomicAdd(&cnt[r], 1);
        atomicAdd(&h[r >> 7], 1);
    }
    __syncthreads();
    for (int j = threadIdx.x; j < NB; j += 256)
        if (h[j]) atomicAdd(&bhist[j], h[j]);
}

// ---------------- exact row scan ----------------
__global__ __launch_bounds__(1024) void k_scan1(const int* __restrict__ cnt, int n,
                                                int* __restrict__ F, int* __restrict__ bsum) {
    __shared__ int s[1024];
    const int tid = threadIdx.x;
    const int i = blockIdx.x * 1024 + tid;
    int v = (i < n) ? cnt[i] : 0;
    s[tid] = v;
    __syncthreads();
    for (int off = 1; off < 1024; off <<= 1) {
        int t = (tid >= off) ? s[tid - off] : 0;
        __syncthreads();
        s[tid] += t;
        __syncthreads();
    }
    if (i < n) F[i] = s[tid] - v;
    if (tid == 1023) bsum[blockIdx.x] = s[tid];
}

__global__ void k_scan2(int* __restrict__ bsum, int nb, int* __restrict__ F, int Ntot, int nnz) {
    if (threadIdx.x == 0 && blockIdx.x == 0) {
        int run = 0;
        for (int b = 0; b < nb; ++b) { int t = bsum[b]; bsum[b] = run; run += t; }
        F[Ntot] = nnz;
    }
}

__global__ __launch_bounds__(1024) void k_scan3(int* __restrict__ F, const int* __restrict__ bsum, int n) {
    int i = blockIdx.x * 1024 + threadIdx.x;
    if (i < n) F[i] += bsum[blockIdx.x];
}

// ---------------- bucket scan (1 block) ----------------
__global__ __launch_bounds__(1024) void k_bscan(const int* __restrict__ bhist,
                                                int* __restrict__ bstart, int* __restrict__ gcur) {
    __shared__ int s[1024];
    const int tid = threadIdx.x;
    int v = (tid < NB) ? bhist[tid] : 0;
    s[tid] = v;
    __syncthreads();
    for (int off = 1; off < 1024; off <<= 1) {
        int t = (tid >= off) ? s[tid - off] : 0;
        __syncthreads();
        s[tid] += t;
        __syncthreads();
    }
    if (tid < NB) {
        bstart[tid + 1] = s[tid];
        gcur[tid] = s[tid] - v;
        if (tid == 0) bstart[0] = 0;
    }
}

// ---------------- stage-1 bucket scatter, LDS-aggregated cursors ----------------
__global__ __launch_bounds__(256) void k_bscatter(
    const int* __restrict__ rows, const int* __restrict__ cols,
    const float* __restrict__ vals, int nnz,
    int* __restrict__ gcur, int2* __restrict__ tmp)
{
    __shared__ int lh[NB];
    __shared__ int lb[NB];
    const int tid = threadIdx.x;
    for (int j = tid; j < NB; j += 256) lh[j] = 0;
    __syncthreads();

    const int base = blockIdx.x * (256 * EPT);
    int r[EPT], c[EPT], lp[EPT];
    float v[EPT];
    #pragma unroll
    for (int j = 0; j < EPT; ++j) {
        const int i = base + j * 256 + tid;
        if (i < nnz) {
            r[j] = rows[i]; c[j] = cols[i]; v[j] = vals[i];
            lp[j] = atomicAdd(&lh[r[j] >> 7], 1);
        }
    }
    __syncthreads();
    for (int j = tid; j < NB; j += 256)
        if (lh[j]) lb[j] = atomicAdd(&gcur[j], lh[j]);
    __syncthreads();
    #pragma unroll
    for (int j = 0; j < EPT; ++j) {
        const int i = base + j * 256 + tid;
        if (i < nnz) {
            int2 e;
            e.x = ((r[j] & 127) << 17) | c[j];
            e.y = __float_as_int(v[j]);
            tmp[lb[r[j] >> 7] + lp[j]] = e;
        }
    }
}

// ---------------- stage-2: exact CSR placement, LDS row cursors only ----------------
__global__ __launch_bounds__(256) void k_sort(
    const int2* __restrict__ tmp, const int* __restrict__ bstart,
    const int* __restrict__ F, int2* __restrict__ sedge)
{
    __shared__ int cnt[RPB];
    const int b = blockIdx.x;
    if (threadIdx.x < RPB) cnt[threadIdx.x] = 0;
    __syncthreads();
    const int s = bstart[b], t = bstart[b + 1];
    for (int i = s + threadIdx.x; i < t; i += 256) {
        const int2 e = tmp[i];
        const int rib = ((unsigned)e.x) >> 17;
        const int col = e.x & 0x1FFFF;
        const int lpos = atomicAdd(&cnt[rib], 1);
        const int row = (b << 7) + rib;
        int2 o; o.x = col; o.y = e.y;
        sedge[F[row] + lpos] = o;
    }
}

// ---------------- fp32 -> bf16 table copy ----------------
__global__ void k_tobf16(const float* __restrict__ in, unsigned short* __restrict__ out, int n8) {
    const int i = blockIdx.x * 256 + threadIdx.x;
    if (i >= n8) return;
    const float4 a = ((const float4*)in)[2 * i];
    const float4 b = ((const float4*)in)[2 * i + 1];
    uint4 p;
    p.x = (unsigned)f2bf(a.x) | ((unsigned)f2bf(a.y) << 16);
    p.y = (unsigned)f2bf(a.z) | ((unsigned)f2bf(a.w) << 16);
    p.z = (unsigned)f2bf(b.x) | ((unsigned)f2bf(b.y) << 16);
    p.w = (unsigned)f2bf(b.z) | ((unsigned)f2bf(b.w) << 16);
    ((uint4*)out)[i] = p;
}

// ---------------- SpMM: row per wave, bf16 gather, fp32 accumulate ----------------
template <int MODE>
__global__ __launch_bounds__(256) void k_spmm(
    const unsigned short* __restrict__ in, unsigned short* __restrict__ outb,
    float* __restrict__ osum,
    const int* __restrict__ F, const int2* __restrict__ sedge, int Ntot)
{
    const int r = blockIdx.x * 4 + (threadIdx.x >> 6);
    if (r >= Ntot) return;
    const int lane = threadIdx.x & 63;
    const int g = lane >> 3, q = lane & 7;
    const int e0 = F[r], e1 = F[r + 1];

    float acc0[8], acc1[8];
    #pragma unroll
    for (int j = 0; j < 8; ++j) { acc0[j] = 0.f; acc1[j] = 0.f; }

    for (int base = e0; base < e1; base += 16) {
        const int ea = base + g, eb = base + 8 + g;
        if (ea < e1) {
            const int2 ed = sedge[ea];
            const float v = __int_as_float(ed.y);
            const uint4 hb = *(const uint4*)(in + (((size_t)ed.x) << 6) + q * 8);
            acc0[0] += v * __uint_as_float(hb.x << 16);
            acc0[1] += v * __uint_as_float(hb.x & 0xFFFF0000u);
            acc0[2] += v * __uint_as_float(hb.y << 16);
            acc0[3] += v * __uint_as_float(hb.y & 0xFFFF0000u);
            acc0[4] += v * __uint_as_float(hb.z << 16);
            acc0[5] += v * __uint_as_float(hb.z & 0xFFFF0000u);
            acc0[6] += v * __uint_as_float(hb.w << 16);
            acc0[7] += v * __uint_as_float(hb.w & 0xFFFF0000u);
        }
        if (eb < e1) {
            const int2 ed = sedge[eb];
            const float v = __int_as_float(ed.y);
            const uint4 hb = *(const uint4*)(in + (((size_t)ed.x) << 6) + q * 8);
            acc1[0] += v * __uint_as_float(hb.x << 16);
            acc1[1] += v * __uint_as_float(hb.x & 0xFFFF0000u);
            acc1[2] += v * __uint_as_float(hb.y << 16);
            acc1[3] += v * __uint_as_float(hb.y & 0xFFFF0000u);
            acc1[4] += v * __uint_as_float(hb.z << 16);
            acc1[5] += v * __uint_as_float(hb.z & 0xFFFF0000u);
            acc1[6] += v * __uint_as_float(hb.w << 16);
            acc1[7] += v * __uint_as_float(hb.w & 0xFFFF0000u);
        }
    }
    #pragma unroll
    for (int j = 0; j < 8; ++j) acc0[j] += acc1[j];

    #pragma unroll
    for (int off = 8; off < 64; off <<= 1)
        #pragma unroll
        for (int j = 0; j < 8; ++j) acc0[j] += __shfl_xor(acc0[j], off, 64);

    if (g == 0) {
        const size_t ob = (((size_t)r) << 6) + q * 8;
        uint4 p;
        p.x = (unsigned)f2bf(acc0[0]) | ((unsigned)f2bf(acc0[1]) << 16);
        p.y = (unsigned)f2bf(acc0[2]) | ((unsigned)f2bf(acc0[3]) << 16);
        p.z = (unsigned)f2bf(acc0[4]) | ((unsigned)f2bf(acc0[5]) << 16);
        p.w = (unsigned)f2bf(acc0[6]) | ((unsigned)f2bf(acc0[7]) << 16);
        *(uint4*)(outb + ob) = p;

        float4 lo = make_float4(acc0[0], acc0[1], acc0[2], acc0[3]);
        float4 hi = make_float4(acc0[4], acc0[5], acc0[6], acc0[7]);
        if (MODE == 0) {
            *(float4*)(osum + ob) = lo;
            *(float4*)(osum + ob + 4) = hi;
        } else {
            float4 a = *(const float4*)(osum + ob);
            float4 b = *(const float4*)(osum + ob + 4);
            a.x += lo.x; a.y += lo.y; a.z += lo.z; a.w += lo.w;
            b.x += hi.x; b.y += hi.y; b.z += hi.z; b.w += hi.w;
            *(float4*)(osum + ob) = a;
            *(float4*)(osum + ob + 4) = b;
        }
    }
}

// ---------------- expmap0(out_sum, project=True): 16 lanes/row, float4 ----------------
__global__ __launch_bounds__(256) void k_expmap_proj(const float* __restrict__ in,
                                                     float* __restrict__ out, int Ntot) {
    const int lane = threadIdx.x & 63;
    const int g = lane >> 4, q = lane & 15;
    const int n = blockIdx.x * 16 + (threadIdx.x >> 6) * 4 + g;
    if (n >= Ntot) return;
    const float4 v = *(const float4*)(in + ((size_t)n << 6) + q * 4);
    const float vx = (q == 0) ? 0.f : v.x;
    float ss = vx * vx + v.y * v.y + v.z * v.z + v.w * v.w;
    #pragma unroll
    for (int off = 1; off < 16; off <<= 1) ss += __shfl_xor(ss, off, 64);
    const float nr = fmaxf(sqrtf(ss), EPSF);
    const float r = sinhf(nr) / nr;
    const float sn = r * sqrtf(ss);
    const float scale = fminf(1.0f, MAXNRM / fmaxf(sn, EPSF));
    const float mult = r * scale;
    float4 o;
    o.x = (q == 0) ? sqrtf(1.0f + mult * mult * ss) : mult * v.x;
    o.y = mult * v.y; o.z = mult * v.z; o.w = mult * v.w;
    *(float4*)(out + ((size_t)n << 6) + q * 4) = o;
}

// ---------------- triple margin loss ----------------
__global__ __launch_bounds__(256) void k_triples(
    const float* __restrict__ O, const int* __restrict__ tri,
    int T, float* __restrict__ slot)
{
    const int lane = threadIdx.x & 63;
    const int g = lane >> 4, q = lane & 15;
    const int wid = blockIdx.x * 4 + (threadIdx.x >> 6);
    const int nwaves = gridDim.x * 4;

    float racc = 0.f;
    for (int tb = wid * 4; tb < T; tb += nwaves * 4) {
        const int t = tb + g;
        const int a = tri[3 * t], p = tri[3 * t + 1], nn = tri[3 * t + 2];
        const float4 av = *(const float4*)(O + (((size_t)a) << 6) + q * 4);
        const float4 pv = *(const float4*)(O + (((size_t)p) << 6) + q * 4);
        const float4 nv = *(const float4*)(O + (((size_t)nn) << 6) + q * 4);
        const float s0 = (q == 0) ? -1.f : 1.f;
        float i1 = s0 * av.x * pv.x + av.y * pv.y + av.z * pv.z + av.w * pv.w;
        float i2 = s0 * av.x * nv.x + av.y * nv.y + av.z * nv.z + av.w * nv.w;
        #pragma unroll
        for (int off = 1; off < 16; off <<= 1) {
            i1 += __shfl_xor(i1, off, 64);
            i2 += __shfl_xor(i2, off, 64);
        }
        if (q == 0) {
            const float d1 = acoshf(fmaxf(-i1, 1.0f + EPSF));
            const float d2 = acoshf(fmaxf(-i2, 1.0f + EPSF));
            const float l = d1 * d1 - d2 * d2 + 0.1f;
            if (l > 0.f) racc += l;
        }
    }

    racc = wsum(racc);
    __shared__ float sb[4];
    if (lane == 0) sb[threadIdx.x >> 6] = racc;
    __syncthreads();
    if (threadIdx.x == 0)
        atomicAdd(&slot[blockIdx.x & 255], sb[0] + sb[1] + sb[2] + sb[3]);
}

// ---------------- finalize ----------------
__global__ void k_final(const float* __restrict__ slots, float* __restrict__ out, int Ntot)
{
    const int tid = threadIdx.x;
    float m = slots[tid], r = slots[256 + tid], k = slots[512 + tid];
    m = wsum(m); r = wsum(r); k = wsum(k);
    __shared__ float sm[4], sr[4], sk[4];
    if ((tid & 63) == 0) { sm[tid >> 6] = m; sr[tid >> 6] = r; sk[tid >> 6] = k; }
    __syncthreads();
    if (tid == 0) {
        const float M = sm[0] + sm[1] + sm[2] + sm[3];
        const float R = sr[0] + sr[1] + sr[2] + sr[3];
        const float K = sk[0] + sk[1] + sk[2] + sk[3];
        const float recon = R / (float)Ntot;
        const float kl = -0.5f * K / ((float)Ntot * 64.0f);
        out[0] = M + 0.1f * (recon + kl);
    }
}

extern "C" void kernel_launch(void* const* d_in, const int* in_sizes, int n_in,
                              void* d_out, int out_size, void* d_ws, size_t ws_size,
                              hipStream_t stream)
{
    const float* emb_user = (const float*)d_in[0];
    const float* emb_item = (const float*)d_in[1];
    const int*   adj_rows = (const int*)d_in[2];
    const int*   adj_cols = (const int*)d_in[3];
    const float* adj_vals = (const float*)d_in[4];
    const int*   triples  = (const int*)d_in[5];
    const float* epsin    = (const float*)d_in[6];
    const float* tW  = (const float*)d_in[7];
    const float* tb  = (const float*)d_in[8];
    const float* tgW = (const float*)d_in[9];
    const float* tgb = (const float*)d_in[10];
    const float* muW = (const float*)d_in[11];
    const float* mub = (const float*)d_in[12];
    const float* lvW = (const float*)d_in[13];
    const float* lvb = (const float*)d_in[14];
    const float* f1W = (const float*)d_in[15];
    const float* f1b = (const float*)d_in[16];
    const float* f2W = (const float*)d_in[17];
    const float* f2b = (const float*)d_in[18];
    const float* dW  = (const float*)d_in[19];
    const float* db  = (const float*)d_in[20];
    const float* dgW = (const float*)d_in[21];
    const float* dgb = (const float*)d_in[22];

    const int Nu = in_sizes[0] / 64, Ni = in_sizes[1] / 64;
    const int N = Nu + Ni;            // 100000
    const int NNZ = in_sizes[4];      // 3200000
    const int T = in_sizes[5] / 3;    // 262144

    float* ws = (float*)d_ws;
    size_t off = 0;
    float* slots = ws + off; off += 1024;            // margin / recon / kl slots
    float* A  = ws + off; off += (size_t)N * 64;     // t/h ; then stage-1 tmp edges; then bf16 {Bh, Hb1}
    float* B  = ws + off; off += (size_t)N * 64;     // m ; then O (expmap output)
    float* C  = ws + off; off += (size_t)N * 64;     // hm ; then out_sum (fp32)
    float* D  = ws + off; off += (size_t)N * 64;     // sedge (exact CSR int2[NNZ])
    float* Hb2f = ws + off; off += (size_t)N * 32;   // bf16 pong buffer
    int*   F  = (int*)(ws + off); off += (size_t)N + 64;   // row starts
    int*   Gc = (int*)(ws + off); off += (size_t)N;        // exact row counts
    int*   bsum   = (int*)(ws + off); off += 1024;
    int*   bstart = (int*)(ws + off); off += 1024;
    int*   bhist  = (int*)(ws + off); off += 1024;
    int*   gcur   = (int*)(ws + off); off += 1024;

    int2* tmp   = (int2*)A;                         // stage-1 bucketed edges (25.6 MB)
    int2* sedge = (int2*)D;                         // exact CSR edges (25.6 MB)
    unsigned short* Bh  = (unsigned short*)A;                         // bf16(m), after k_sort
    unsigned short* Hb1 = (unsigned short*)A + (size_t)N * 64;        // bf16 ping
    unsigned short* Hb2 = (unsigned short*)Hb2f;                      // bf16 pong

    hipMemsetAsync(slots, 0, 1024 * sizeof(float), stream);
    hipMemsetAsync(bhist, 0, 1024 * sizeof(int), stream);
    hipMemsetAsync(Gc, 0, (size_t)N * sizeof(int), stream);

    const int nb32 = N / 32;          // 3125
    const int nb16 = (N + 15) / 16;   // 6250

    // dense chain
    k_logmap<<<nb16, 256, 0, stream>>>(emb_user, emb_item, Nu, N, A);
    k_moe<<<nb32, 256, 0, stream>>>(A, B, tW, tb, tgW, tgb);
    k_vae<<<nb32, 256, 0, stream>>>(B, A, epsin, muW, mub, lvW, lvb, slots + 512);
    k_ffn<<<nb32, 256, 0, stream>>>(A, f1W, f1b, f2W, f2b);
    k_moe<<<nb32, 256, 0, stream>>>(A, C, dW, db, dgW, dgb);
    k_recon<<<nb16, 256, 0, stream>>>(C, B, N, slots + 256);

    // CSR build
    k_count<<<1024, 256, 0, stream>>>(adj_rows, NNZ, Gc, bhist);
    const int nsb = (N + 1023) / 1024;   // 98
    k_scan1<<<nsb, 1024, 0, stream>>>(Gc, N, F, bsum);
    k_scan2<<<1, 64, 0, stream>>>(bsum, nsb, F, N, NNZ);
    k_scan3<<<nsb, 1024, 0, stream>>>(F, bsum, N);
    k_bscan<<<1, 1024, 0, stream>>>(bhist, bstart, gcur);
    const int ns1 = (NNZ + 256 * EPT - 1) / (256 * EPT);   // 782
    k_bscatter<<<ns1, 256, 0, stream>>>(adj_rows, adj_cols, adj_vals, NNZ, gcur, tmp);
    k_sort<<<NB, 256, 0, stream>>>(tmp, bstart, F, sedge);

    // bf16 table for layer-1 gather (A's tmp is dead after k_sort)
    k_tobf16<<<(N * 64 / 8 + 255) / 256, 256, 0, stream>>>(B, Bh, N * 8);

    // 3-layer spmm chain, bf16 gather + fp32 out_sum in C
    k_spmm<0><<<(N + 3) / 4, 256, 0, stream>>>(Bh,  Hb1, C, F, sedge, N);
    k_spmm<1><<<(N + 3) / 4, 256, 0, stream>>>(Hb1, Hb2, C, F, sedge, N);
    k_spmm<1><<<(N + 3) / 4, 256, 0, stream>>>(Hb2, Bh,  C, F, sedge, N);

    k_expmap_proj<<<nb16, 256, 0, stream>>>(C, B, N);
    k_triples<<<2048, 256, 0, stream>>>(B, triples, T, slots);
    k_final<<<1, 256, 0, stream>>>(slots, (float*)d_out, N);
}

// Round 6
// 733.977 us; speedup vs baseline: 7.3607x; 1.1973x over previous
//
#include <hip/hip_runtime.h>
#include <math.h>

#define EPSF 1e-7f
#define MAXNRM 10.0f
#define NB 782          // ceil(100000/128) buckets
#define RPB 128         // rows per bucket
#define EPT 16          // edges per thread in stage-1 scatter

__device__ __forceinline__ float wsum(float v) {
    #pragma unroll
    for (int off = 32; off > 0; off >>= 1) v += __shfl_xor(v, off, 64);
    return v;
}

__device__ __forceinline__ unsigned short f2bf(float x) {   // RNE
    unsigned u = __float_as_uint(x);
    unsigned r = (u + 0x7FFFu + ((u >> 16) & 1u)) >> 16;
    return (unsigned short)r;
}

// ---------------- logmap0 of embeddings -> t (16 lanes/row, float4) ----------------
__global__ __launch_bounds__(256) void k_logmap(const float* __restrict__ eu, const float* __restrict__ ei,
                                                int Nu, int Ntot, float* __restrict__ out) {
    const int lane = threadIdx.x & 63;
    const int g = lane >> 4, q = lane & 15;
    const int n = blockIdx.x * 16 + (threadIdx.x >> 6) * 4 + g;
    if (n >= Ntot) return;
    const float* src = (n < Nu) ? (eu + (size_t)n * 64) : (ei + (size_t)(n - Nu) * 64);
    const float x0 = src[0];
    const float alpha = fmaxf(x0, 1.0f + EPSF);
    const float coef = acoshf(alpha) / sqrtf(fmaxf(alpha * alpha - 1.0f, EPSF));
    const float4 v = *(const float4*)(src + q * 4);
    float4 o;
    o.x = (q == 0) ? 0.0f : coef * v.x;
    o.y = coef * v.y; o.z = coef * v.z; o.w = coef * v.w;
    *(float4*)(out + ((size_t)n << 6) + q * 4) = o;
}

// ---------------- MoE ----------------
__global__ __launch_bounds__(256) void k_moe(
    const float* __restrict__ X, float* __restrict__ Y,
    const float* __restrict__ W, const float* __restrict__ Bb,
    const float* __restrict__ GW, const float* __restrict__ GB)
{
    __shared__ float sX[32][68];
    __shared__ float sG[32][8];
    const int tid = threadIdx.x;
    const int n0 = blockIdx.x * 32;

    for (int i = tid; i < 2048; i += 256)
        sX[i >> 6][i & 63] = X[(size_t)n0 * 64 + i];
    __syncthreads();

    {
        const int n = tid >> 3, e = tid & 7;
        float lg = GB[e];
        #pragma unroll 16
        for (int d = 0; d < 64; ++d) lg += sX[n][d] * GW[d * 8 + e];
        sG[n][e] = lg;
    }
    __syncthreads();
    if (tid < 32) {
        float mx = -1e30f;
        #pragma unroll
        for (int e = 0; e < 8; ++e) mx = fmaxf(mx, sG[tid][e]);
        float ex[8]; float s = 0.f;
        #pragma unroll
        for (int e = 0; e < 8; ++e) { ex[e] = expf(sG[tid][e] - mx); s += ex[e]; }
        float inv = 1.0f / s;
        #pragma unroll
        for (int e = 0; e < 8; ++e) sG[tid][e] = ex[e] * inv;
    }
    __syncthreads();

    const int o = tid & 63, nq = tid >> 6;
    float y[8][8];
    #pragma unroll
    for (int k = 0; k < 8; ++k)
        #pragma unroll
        for (int e = 0; e < 8; ++e) y[k][e] = 0.f;

    for (int dc = 0; dc < 16; ++dc) {
        float a[8][4];
        #pragma unroll
        for (int k = 0; k < 8; ++k) {
            float4 av = *(const float4*)(&sX[nq + 4 * k][dc * 4]);
            a[k][0] = av.x; a[k][1] = av.y; a[k][2] = av.z; a[k][3] = av.w;
        }
        #pragma unroll
        for (int e = 0; e < 8; ++e) {
            #pragma unroll
            for (int j = 0; j < 4; ++j) {
                const float w = W[(((size_t)e) << 12) + (size_t)(dc * 4 + j) * 64 + o];
                #pragma unroll
                for (int k = 0; k < 8; ++k) y[k][e] += a[k][j] * w;
            }
        }
    }

    #pragma unroll
    for (int k = 0; k < 8; ++k) {
        const int n = nq + 4 * k;
        float acc = 0.f;
        #pragma unroll
        for (int e = 0; e < 8; ++e) acc += sG[n][e] * (y[k][e] + Bb[e * 64 + o]);
        Y[(size_t)(n0 + n) * 64 + o] = acc;
    }
}

// ---------------- VAE mid ----------------
__global__ __launch_bounds__(256) void k_vae(
    const float* __restrict__ M, float* __restrict__ Hout,
    const float* __restrict__ EPSN,
    const float* __restrict__ muW, const float* __restrict__ mub,
    const float* __restrict__ lvW, const float* __restrict__ lvb,
    float* __restrict__ klslot)
{
    __shared__ float sM[32][68];
    __shared__ float sC[32];
    const int tid = threadIdx.x;
    const int n0 = blockIdx.x * 32;

    for (int i = tid; i < 2048; i += 256)
        sM[i >> 6][i & 63] = M[(size_t)n0 * 64 + i];
    __syncthreads();

    const int o = tid & 63, nq = tid >> 6;
    float ymu[8], ylv[8];
    #pragma unroll
    for (int k = 0; k < 8; ++k) { ymu[k] = 0.f; ylv[k] = 0.f; }

    for (int dc = 0; dc < 16; ++dc) {
        float a[8][4];
        #pragma unroll
        for (int k = 0; k < 8; ++k) {
            float4 av = *(const float4*)(&sM[nq + 4 * k][dc * 4]);
            a[k][0] = av.x; a[k][1] = av.y; a[k][2] = av.z; a[k][3] = av.w;
        }
        #pragma unroll
        for (int j = 0; j < 4; ++j) {
            const float wm = muW[(size_t)(dc * 4 + j) * 64 + o];
            const float wl = lvW[(size_t)(dc * 4 + j) * 64 + o];
            #pragma unroll
            for (int k = 0; k < 8; ++k) { ymu[k] += a[k][j] * wm; ylv[k] += a[k][j] * wl; }
        }
    }

    float u[8];
    float klp = 0.f;
    #pragma unroll
    for (int k = 0; k < 8; ++k) {
        const int n = nq + 4 * k;
        const float mu = ymu[k] + mub[o];
        const float lv = ylv[k] + lvb[o];
        const float elv = expf(lv);
        klp += 1.0f + lv - mu * mu - elv;
        u[k] = mu + EPSN[(size_t)(n0 + n) * 64 + o] * expf(0.5f * lv);
    }
    klp = wsum(klp);
    if ((tid & 63) == 0) atomicAdd(&klslot[(blockIdx.x * 4 + nq) & 255], klp);

    __syncthreads();
    #pragma unroll
    for (int k = 0; k < 8; ++k) sM[nq + 4 * k][o] = u[k];
    __syncthreads();

    {   // per-row norm: 8 lanes per row
        const int r2 = tid >> 3, j = tid & 7;
        const float4 a = *(const float4*)(&sM[r2][j * 8]);
        const float4 b = *(const float4*)(&sM[r2][j * 8 + 4]);
        const float ax = (j == 0) ? 0.f : a.x;
        float ss = ax * ax + a.y * a.y + a.z * a.z + a.w * a.w
                 + b.x * b.x + b.y * b.y + b.z * b.z + b.w * b.w;
        #pragma unroll
        for (int off = 1; off < 8; off <<= 1) ss += __shfl_xor(ss, off, 64);
        if (j == 0) {
            const float nr = fmaxf(sqrtf(ss), EPSF);
            const float r = sinhf(nr) / nr;
            const float sn = r * sqrtf(ss);
            const float scale = fminf(1.0f, MAXNRM / fmaxf(sn, EPSF));
            const float mult = r * scale;
            const float s2 = mult * mult * ss;
            const float z0 = sqrtf(1.0f + s2);
            const float alpha = fmaxf(z0, 1.0f + EPSF);
            const float coef = acoshf(alpha) / sqrtf(fmaxf(alpha * alpha - 1.0f, EPSF));
            sC[r2] = coef * mult;
        }
    }
    __syncthreads();

    #pragma unroll
    for (int k = 0; k < 8; ++k) {
        const int n = nq + 4 * k;
        Hout[(size_t)(n0 + n) * 64 + o] = (o == 0) ? 0.f : sC[n] * sM[n][o];
    }
}

// ---------------- FFN ----------------
__global__ __launch_bounds__(256) void k_ffn(
    float* __restrict__ Hio,
    const float* __restrict__ f1W, const float* __restrict__ f1b,
    const float* __restrict__ f2W, const float* __restrict__ f2b)
{
    __shared__ float sH[32][68];
    __shared__ float sH1[32][132];
    const int tid = threadIdx.x;
    const int n0 = blockIdx.x * 32;

    for (int i = tid; i < 2048; i += 256)
        sH[i >> 6][i & 63] = Hio[(size_t)n0 * 64 + i];
    __syncthreads();

    const int o = tid & 63, nq = tid >> 6;
    float y0[8], y1[8];
    #pragma unroll
    for (int k = 0; k < 8; ++k) { y0[k] = 0.f; y1[k] = 0.f; }

    for (int dc = 0; dc < 16; ++dc) {
        float a[8][4];
        #pragma unroll
        for (int k = 0; k < 8; ++k) {
            float4 av = *(const float4*)(&sH[nq + 4 * k][dc * 4]);
            a[k][0] = av.x; a[k][1] = av.y; a[k][2] = av.z; a[k][3] = av.w;
        }
        #pragma unroll
        for (int j = 0; j < 4; ++j) {
            const float w0 = f1W[(size_t)(dc * 4 + j) * 128 + o];
            const float w1 = f1W[(size_t)(dc * 4 + j) * 128 + 64 + o];
            #pragma unroll
            for (int k = 0; k < 8; ++k) { y0[k] += a[k][j] * w0; y1[k] += a[k][j] * w1; }
        }
    }
    #pragma unroll
    for (int k = 0; k < 8; ++k) {
        const int n = nq + 4 * k;
        sH1[n][o] = fmaxf(y0[k] + f1b[o], 0.f);
        sH1[n][64 + o] = fmaxf(y1[k] + f1b[64 + o], 0.f);
    }
    __syncthreads();

    float y2[8];
    #pragma unroll
    for (int k = 0; k < 8; ++k) y2[k] = 0.f;
    for (int dc = 0; dc < 32; ++dc) {
        float a[8][4];
        #pragma unroll
        for (int k = 0; k < 8; ++k) {
            float4 av = *(const float4*)(&sH1[nq + 4 * k][dc * 4]);
            a[k][0] = av.x; a[k][1] = av.y; a[k][2] = av.z; a[k][3] = av.w;
        }
        #pragma unroll
        for (int j = 0; j < 4; ++j) {
            const float w = f2W[(size_t)(dc * 4 + j) * 64 + o];
            #pragma unroll
            for (int k = 0; k < 8; ++k) y2[k] += a[k][j] * w;
        }
    }
    #pragma unroll
    for (int k = 0; k < 8; ++k)
        Hio[(size_t)(n0 + nq + 4 * k) * 64 + o] = y2[k] + f2b[o];
}

// ---------------- recon loss: 16 lanes/node, dot-product identity ----------------
__global__ __launch_bounds__(256) void k_recon(
    const float* __restrict__ HM, const float* __restrict__ M,
    int Ntot, float* __restrict__ slot)
{
    const int lane = threadIdx.x & 63;
    const int g = lane >> 4, q = lane & 15;
    const int n = blockIdx.x * 16 + (threadIdx.x >> 6) * 4 + g;

    float ssh = 0.f, ssm = 0.f, dot = 0.f;
    if (n < Ntot) {
        const float4 h = *(const float4*)(HM + ((size_t)n << 6) + q * 4);
        const float4 m = *(const float4*)(M  + ((size_t)n << 6) + q * 4);
        const float hx = (q == 0) ? 0.f : h.x;
        const float mx = (q == 0) ? 0.f : m.x;
        ssh = hx * hx + h.y * h.y + h.z * h.z + h.w * h.w;
        ssm = mx * mx + m.y * m.y + m.z * m.z + m.w * m.w;
        dot = hx * mx + h.y * m.y + h.z * m.z + h.w * m.w;
    }
    #pragma unroll
    for (int off = 1; off < 16; off <<= 1) {
        ssh += __shfl_xor(ssh, off, 64);
        ssm += __shfl_xor(ssm, off, 64);
        dot += __shfl_xor(dot, off, 64);
    }

    float part = 0.f;
    if (q == 0 && n < Ntot) {
        const float nm = fmaxf(sqrtf(ssm), EPSF);
        const float em0 = coshf(nm);
        const float rm = sinhf(nm) / nm;

        const float nh = fmaxf(sqrtf(ssh), EPSF);
        const float rh = sinhf(nh) / nh;
        const float sn = rh * sqrtf(ssh);
        const float scale = fminf(1.0f, MAXNRM / fmaxf(sn, EPSF));
        const float mult = rh * scale;
        const float rec0 = sqrtf(1.0f + mult * mult * ssh);

        const float inner = mult * rm * dot - rec0 * em0;
        const float dd = acoshf(fmaxf(-inner, 1.0f + EPSF));
        part = dd * dd;
    }
    part = wsum(part);
    __shared__ float sb[4];
    if (lane == 0) sb[threadIdx.x >> 6] = part;
    __syncthreads();
    if (threadIdx.x == 0)
        atomicAdd(&slot[blockIdx.x & 255], sb[0] + sb[1] + sb[2] + sb[3]);
}

// ---------------- bucket histogram only (no per-row global atomics) ----------------
__global__ __launch_bounds__(256) void k_bhist(const int* __restrict__ rows, int nnz,
                                               int* __restrict__ bhist) {
    __shared__ int h[NB];
    for (int j = threadIdx.x; j < NB; j += 256) h[j] = 0;
    __syncthreads();
    for (int i = blockIdx.x * 256 + threadIdx.x; i < nnz; i += gridDim.x * 256)
        atomicAdd(&h[rows[i] >> 7], 1);
    __syncthreads();
    for (int j = threadIdx.x; j < NB; j += 256)
        if (h[j]) atomicAdd(&bhist[j], h[j]);
}

// ---------------- bucket scan (1 block) ----------------
__global__ __launch_bounds__(1024) void k_bscan(const int* __restrict__ bhist,
                                                int* __restrict__ bstart, int* __restrict__ gcur) {
    __shared__ int s[1024];
    const int tid = threadIdx.x;
    int v = (tid < NB) ? bhist[tid] : 0;
    s[tid] = v;
    __syncthreads();
    for (int off = 1; off < 1024; off <<= 1) {
        int t = (tid >= off) ? s[tid - off] : 0;
        __syncthreads();
        s[tid] += t;
        __syncthreads();
    }
    if (tid < NB) {
        bstart[tid + 1] = s[tid];
        gcur[tid] = s[tid] - v;
        if (tid == 0) bstart[0] = 0;
    }
}

// ---------------- stage-1 bucket scatter, LDS-aggregated cursors ----------------
__global__ __launch_bounds__(256) void k_bscatter(
    const int* __restrict__ rows, const int* __restrict__ cols,
    const float* __restrict__ vals, int nnz,
    int* __restrict__ gcur, int2* __restrict__ tmp)
{
    __shared__ int lh[NB];
    __shared__ int lb[NB];
    const int tid = threadIdx.x;
    for (int j = tid; j < NB; j += 256) lh[j] = 0;
    __syncthreads();

    const int base = blockIdx.x * (256 * EPT);
    int r[EPT], c[EPT], lp[EPT];
    float v[EPT];
    #pragma unroll
    for (int j = 0; j < EPT; ++j) {
        const int i = base + j * 256 + tid;
        if (i < nnz) {
            r[j] = rows[i]; c[j] = cols[i]; v[j] = vals[i];
            lp[j] = atomicAdd(&lh[r[j] >> 7], 1);
        }
    }
    __syncthreads();
    for (int j = tid; j < NB; j += 256)
        if (lh[j]) lb[j] = atomicAdd(&gcur[j], lh[j]);
    __syncthreads();
    #pragma unroll
    for (int j = 0; j < EPT; ++j) {
        const int i = base + j * 256 + tid;
        if (i < nnz) {
            int2 e;
            e.x = ((r[j] & 127) << 17) | c[j];
            e.y = __float_as_int(v[j]);
            tmp[lb[r[j] >> 7] + lp[j]] = e;
        }
    }
}

// ---------------- stage-2: two-pass CSR placement + F derivation (no global scan) ----------------
__global__ __launch_bounds__(256) void k_sort(
    const int2* __restrict__ tmp, const int* __restrict__ bstart,
    int2* __restrict__ sedge, int* __restrict__ Fout, int Ntot, int nnz)
{
    __shared__ int cnt[RPB];
    __shared__ int excl[RPB];
    const int b = blockIdx.x;
    const int tid = threadIdx.x;
    if (tid < RPB) cnt[tid] = 0;
    __syncthreads();
    const int s = bstart[b], t = bstart[b + 1];

    // pass A: per-row counts
    for (int i = s + tid; i < t; i += 256)
        atomicAdd(&cnt[((unsigned)tmp[i].x) >> 17], 1);
    __syncthreads();

    // exclusive scan of 128 counts on wave 0 (2 values/lane)
    if (tid < 64) {
        const int a0 = cnt[2 * tid], a1 = cnt[2 * tid + 1];
        const int pairsum = a0 + a1;
        int run = pairsum;
        #pragma unroll
        for (int off = 1; off < 64; off <<= 1) {
            const int vv = __shfl_up(run, off, 64);
            if (tid >= off) run += vv;
        }
        const int ep = run - pairsum;
        excl[2 * tid] = ep;
        excl[2 * tid + 1] = ep + a0;
    }
    __syncthreads();

    // write row starts (coalesced)
    const int r0 = b << 7;
    if (tid < RPB) {
        const int r = r0 + tid;
        if (r < Ntot) Fout[r] = s + excl[tid];
        cnt[tid] = excl[tid];              // reuse as cursor
    }
    if (b == NB - 1 && tid == 0) Fout[Ntot] = nnz;
    __syncthreads();

    // pass B: place edges
    for (int i = s + tid; i < t; i += 256) {
        const int2 e = tmp[i];
        const int rib = ((unsigned)e.x) >> 17;
        const int lpos = atomicAdd(&cnt[rib], 1);
        int2 o; o.x = e.x & 0x1FFFF; o.y = e.y;
        sedge[s + lpos] = o;
    }
}

// ---------------- fp32 -> bf16 table copy ----------------
__global__ void k_tobf16(const float* __restrict__ in, unsigned short* __restrict__ out, int n8) {
    const int i = blockIdx.x * 256 + threadIdx.x;
    if (i >= n8) return;
    const float4 a = ((const float4*)in)[2 * i];
    const float4 b = ((const float4*)in)[2 * i + 1];
    uint4 p;
    p.x = (unsigned)f2bf(a.x) | ((unsigned)f2bf(a.y) << 16);
    p.y = (unsigned)f2bf(a.z) | ((unsigned)f2bf(a.w) << 16);
    p.z = (unsigned)f2bf(b.x) | ((unsigned)f2bf(b.y) << 16);
    p.w = (unsigned)f2bf(b.z) | ((unsigned)f2bf(b.w) << 16);
    ((uint4*)out)[i] = p;
}

// ---------------- SpMM: row per wave, bf16 gather, fp32 accumulate ----------------
template <int MODE>
__global__ __launch_bounds__(256) void k_spmm(
    const unsigned short* __restrict__ in, unsigned short* __restrict__ outb,
    float* __restrict__ osum,
    const int* __restrict__ F, const int2* __restrict__ sedge, int Ntot)
{
    const int r = blockIdx.x * 4 + (threadIdx.x >> 6);
    if (r >= Ntot) return;
    const int lane = threadIdx.x & 63;
    const int g = lane >> 3, q = lane & 7;
    const int e0 = F[r], e1 = F[r + 1];

    float acc0[8], acc1[8];
    #pragma unroll
    for (int j = 0; j < 8; ++j) { acc0[j] = 0.f; acc1[j] = 0.f; }

    for (int base = e0; base < e1; base += 16) {
        const int ea = base + g, eb = base + 8 + g;
        if (ea < e1) {
            const int2 ed = sedge[ea];
            const float v = __int_as_float(ed.y);
            const uint4 hb = *(const uint4*)(in + (((size_t)ed.x) << 6) + q * 8);
            acc0[0] += v * __uint_as_float(hb.x << 16);
            acc0[1] += v * __uint_as_float(hb.x & 0xFFFF0000u);
            acc0[2] += v * __uint_as_float(hb.y << 16);
            acc0[3] += v * __uint_as_float(hb.y & 0xFFFF0000u);
            acc0[4] += v * __uint_as_float(hb.z << 16);
            acc0[5] += v * __uint_as_float(hb.z & 0xFFFF0000u);
            acc0[6] += v * __uint_as_float(hb.w << 16);
            acc0[7] += v * __uint_as_float(hb.w & 0xFFFF0000u);
        }
        if (eb < e1) {
            const int2 ed = sedge[eb];
            const float v = __int_as_float(ed.y);
            const uint4 hb = *(const uint4*)(in + (((size_t)ed.x) << 6) + q * 8);
            acc1[0] += v * __uint_as_float(hb.x << 16);
            acc1[1] += v * __uint_as_float(hb.x & 0xFFFF0000u);
            acc1[2] += v * __uint_as_float(hb.y << 16);
            acc1[3] += v * __uint_as_float(hb.y & 0xFFFF0000u);
            acc1[4] += v * __uint_as_float(hb.z << 16);
            acc1[5] += v * __uint_as_float(hb.z & 0xFFFF0000u);
            acc1[6] += v * __uint_as_float(hb.w << 16);
            acc1[7] += v * __uint_as_float(hb.w & 0xFFFF0000u);
        }
    }
    #pragma unroll
    for (int j = 0; j < 8; ++j) acc0[j] += acc1[j];

    #pragma unroll
    for (int off = 8; off < 64; off <<= 1)
        #pragma unroll
        for (int j = 0; j < 8; ++j) acc0[j] += __shfl_xor(acc0[j], off, 64);

    if (g == 0) {
        const size_t ob = (((size_t)r) << 6) + q * 8;
        uint4 p;
        p.x = (unsigned)f2bf(acc0[0]) | ((unsigned)f2bf(acc0[1]) << 16);
        p.y = (unsigned)f2bf(acc0[2]) | ((unsigned)f2bf(acc0[3]) << 16);
        p.z = (unsigned)f2bf(acc0[4]) | ((unsigned)f2bf(acc0[5]) << 16);
        p.w = (unsigned)f2bf(acc0[6]) | ((unsigned)f2bf(acc0[7]) << 16);
        *(uint4*)(outb + ob) = p;

        float4 lo = make_float4(acc0[0], acc0[1], acc0[2], acc0[3]);
        float4 hi = make_float4(acc0[4], acc0[5], acc0[6], acc0[7]);
        if (MODE == 0) {
            *(float4*)(osum + ob) = lo;
            *(float4*)(osum + ob + 4) = hi;
        } else {
            float4 a = *(const float4*)(osum + ob);
            float4 b = *(const float4*)(osum + ob + 4);
            a.x += lo.x; a.y += lo.y; a.z += lo.z; a.w += lo.w;
            b.x += hi.x; b.y += hi.y; b.z += hi.z; b.w += hi.w;
            *(float4*)(osum + ob) = a;
            *(float4*)(osum + ob + 4) = b;
        }
    }
}

// ---------------- expmap0(out_sum, project=True): 16 lanes/row, float4 ----------------
__global__ __launch_bounds__(256) void k_expmap_proj(const float* __restrict__ in,
                                                     float* __restrict__ out, int Ntot) {
    const int lane = threadIdx.x & 63;
    const int g = lane >> 4, q = lane & 15;
    const int n = blockIdx.x * 16 + (threadIdx.x >> 6) * 4 + g;
    if (n >= Ntot) return;
    const float4 v = *(const float4*)(in + ((size_t)n << 6) + q * 4);
    const float vx = (q == 0) ? 0.f : v.x;
    float ss = vx * vx + v.y * v.y + v.z * v.z + v.w * v.w;
    #pragma unroll
    for (int off = 1; off < 16; off <<= 1) ss += __shfl_xor(ss, off, 64);
    const float nr = fmaxf(sqrtf(ss), EPSF);
    const float r = sinhf(nr) / nr;
    const float sn = r * sqrtf(ss);
    const float scale = fminf(1.0f, MAXNRM / fmaxf(sn, EPSF));
    const float mult = r * scale;
    float4 o;
    o.x = (q == 0) ? sqrtf(1.0f + mult * mult * ss) : mult * v.x;
    o.y = mult * v.y; o.z = mult * v.z; o.w = mult * v.w;
    *(float4*)(out + ((size_t)n << 6) + q * 4) = o;
}

// ---------------- triple margin loss ----------------
__global__ __launch_bounds__(256) void k_triples(
    const float* __restrict__ O, const int* __restrict__ tri,
    int T, float* __restrict__ slot)
{
    const int lane = threadIdx.x & 63;
    const int g = lane >> 4, q = lane & 15;
    const int wid = blockIdx.x * 4 + (threadIdx.x >> 6);
    const int nwaves = gridDim.x * 4;

    float racc = 0.f;
    for (int tb = wid * 4; tb < T; tb += nwaves * 4) {
        const int t = tb + g;
        const int a = tri[3 * t], p = tri[3 * t + 1], nn = tri[3 * t + 2];
        const float4 av = *(const float4*)(O + (((size_t)a) << 6) + q * 4);
        const float4 pv = *(const float4*)(O + (((size_t)p) << 6) + q * 4);
        const float4 nv = *(const float4*)(O + (((size_t)nn) << 6) + q * 4);
        const float s0 = (q == 0) ? -1.f : 1.f;
        float i1 = s0 * av.x * pv.x + av.y * pv.y + av.z * pv.z + av.w * pv.w;
        float i2 = s0 * av.x * nv.x + av.y * nv.y + av.z * nv.z + av.w * nv.w;
        #pragma unroll
        for (int off = 1; off < 16; off <<= 1) {
            i1 += __shfl_xor(i1, off, 64);
            i2 += __shfl_xor(i2, off, 64);
        }
        if (q == 0) {
            const float d1 = acoshf(fmaxf(-i1, 1.0f + EPSF));
            const float d2 = acoshf(fmaxf(-i2, 1.0f + EPSF));
            const float l = d1 * d1 - d2 * d2 + 0.1f;
            if (l > 0.f) racc += l;
        }
    }

    racc = wsum(racc);
    __shared__ float sb[4];
    if (lane == 0) sb[threadIdx.x >> 6] = racc;
    __syncthreads();
    if (threadIdx.x == 0)
        atomicAdd(&slot[blockIdx.x & 255], sb[0] + sb[1] + sb[2] + sb[3]);
}

// ---------------- finalize ----------------
__global__ void k_final(const float* __restrict__ slots, float* __restrict__ out, int Ntot)
{
    const int tid = threadIdx.x;
    float m = slots[tid], r = slots[256 + tid], k = slots[512 + tid];
    m = wsum(m); r = wsum(r); k = wsum(k);
    __shared__ float sm[4], sr[4], sk[4];
    if ((tid & 63) == 0) { sm[tid >> 6] = m; sr[tid >> 6] = r; sk[tid >> 6] = k; }
    __syncthreads();
    if (tid == 0) {
        const float M = sm[0] + sm[1] + sm[2] + sm[3];
        const float R = sr[0] + sr[1] + sr[2] + sr[3];
        const float K = sk[0] + sk[1] + sk[2] + sk[3];
        const float recon = R / (float)Ntot;
        const float kl = -0.5f * K / ((float)Ntot * 64.0f);
        out[0] = M + 0.1f * (recon + kl);
    }
}

extern "C" void kernel_launch(void* const* d_in, const int* in_sizes, int n_in,
                              void* d_out, int out_size, void* d_ws, size_t ws_size,
                              hipStream_t stream)
{
    const float* emb_user = (const float*)d_in[0];
    const float* emb_item = (const float*)d_in[1];
    const int*   adj_rows = (const int*)d_in[2];
    const int*   adj_cols = (const int*)d_in[3];
    const float* adj_vals = (const float*)d_in[4];
    const int*   triples  = (const int*)d_in[5];
    const float* epsin    = (const float*)d_in[6];
    const float* tW  = (const float*)d_in[7];
    const float* tb  = (const float*)d_in[8];
    const float* tgW = (const float*)d_in[9];
    const float* tgb = (const float*)d_in[10];
    const float* muW = (const float*)d_in[11];
    const float* mub = (const float*)d_in[12];
    const float* lvW = (const float*)d_in[13];
    const float* lvb = (const float*)d_in[14];
    const float* f1W = (const float*)d_in[15];
    const float* f1b = (const float*)d_in[16];
    const float* f2W = (const float*)d_in[17];
    const float* f2b = (const float*)d_in[18];
    const float* dW  = (const float*)d_in[19];
    const float* db  = (const float*)d_in[20];
    const float* dgW = (const float*)d_in[21];
    const float* dgb = (const float*)d_in[22];

    const int Nu = in_sizes[0] / 64, Ni = in_sizes[1] / 64;
    const int N = Nu + Ni;            // 100000
    const int NNZ = in_sizes[4];      // 3200000
    const int T = in_sizes[5] / 3;    // 262144

    float* ws = (float*)d_ws;
    size_t off = 0;
    float* slots = ws + off; off += 1024;            // margin / recon / kl slots
    float* A  = ws + off; off += (size_t)N * 64;     // t/h ; then stage-1 tmp edges; then bf16 {Bh, Hb1}
    float* B  = ws + off; off += (size_t)N * 64;     // m ; then O (expmap output)
    float* C  = ws + off; off += (size_t)N * 64;     // hm ; then out_sum (fp32)
    float* D  = ws + off; off += (size_t)N * 64;     // sedge (exact CSR int2[NNZ])
    float* Hb2f = ws + off; off += (size_t)N * 32;   // bf16 pong buffer
    int*   F  = (int*)(ws + off); off += (size_t)N + 64;   // row starts
    int*   bstart = (int*)(ws + off); off += 1024;
    int*   bhist  = (int*)(ws + off); off += 1024;
    int*   gcur   = (int*)(ws + off); off += 1024;

    int2* tmp   = (int2*)A;                         // stage-1 bucketed edges (25.6 MB)
    int2* sedge = (int2*)D;                         // exact CSR edges (25.6 MB)
    unsigned short* Bh  = (unsigned short*)A;                         // bf16(m), after k_sort
    unsigned short* Hb1 = (unsigned short*)A + (size_t)N * 64;        // bf16 ping
    unsigned short* Hb2 = (unsigned short*)Hb2f;                      // bf16 pong

    hipMemsetAsync(slots, 0, 1024 * sizeof(float), stream);
    hipMemsetAsync(bhist, 0, 1024 * sizeof(int), stream);

    const int nb32 = N / 32;          // 3125
    const int nb16 = (N + 15) / 16;   // 6250

    // dense chain
    k_logmap<<<nb16, 256, 0, stream>>>(emb_user, emb_item, Nu, N, A);
    k_moe<<<nb32, 256, 0, stream>>>(A, B, tW, tb, tgW, tgb);
    k_vae<<<nb32, 256, 0, stream>>>(B, A, epsin, muW, mub, lvW, lvb, slots + 512);
    k_ffn<<<nb32, 256, 0, stream>>>(A, f1W, f1b, f2W, f2b);
    k_moe<<<nb32, 256, 0, stream>>>(A, C, dW, db, dgW, dgb);
    k_recon<<<nb16, 256, 0, stream>>>(C, B, N, slots + 256);

    // CSR build (bucket-local; no global row scan)
    k_bhist<<<512, 256, 0, stream>>>(adj_rows, NNZ, bhist);
    k_bscan<<<1, 1024, 0, stream>>>(bhist, bstart, gcur);
    const int ns1 = (NNZ + 256 * EPT - 1) / (256 * EPT);   // 782
    k_bscatter<<<ns1, 256, 0, stream>>>(adj_rows, adj_cols, adj_vals, NNZ, gcur, tmp);
    k_sort<<<NB, 256, 0, stream>>>(tmp, bstart, sedge, F, N, NNZ);

    // bf16 table for layer-1 gather (A's tmp is dead after k_sort)
    k_tobf16<<<(N * 64 / 8 + 255) / 256, 256, 0, stream>>>(B, Bh, N * 8);

    // 3-layer spmm chain, bf16 gather + fp32 out_sum in C
    k_spmm<0><<<(N + 3) / 4, 256, 0, stream>>>(Bh,  Hb1, C, F, sedge, N);
    k_spmm<1><<<(N + 3) / 4, 256, 0, stream>>>(Hb1, Hb2, C, F, sedge, N);
    k_spmm<1><<<(N + 3) / 4, 256, 0, stream>>>(Hb2, Bh,  C, F, sedge, N);

    k_expmap_proj<<<nb16, 256, 0, stream>>>(C, B, N);
    k_triples<<<2048, 256, 0, stream>>>(B, triples, T, slots);
    k_final<<<1, 256, 0, stream>>>(slots, (float*)d_out, N);
}

// Round 7
// 661.634 us; speedup vs baseline: 8.1655x; 1.1093x over previous
//
#include <hip/hip_runtime.h>
#include <math.h>

#define EPSF 1e-7f
#define MAXNRM 10.0f
#define NB 782          // ceil(100000/128) buckets
#define RPB 128         // rows per bucket
#define EPT 16          // edges per thread in stage-1 scatter

using bf16x8 = __attribute__((ext_vector_type(8))) short;
using f32x4  = __attribute__((ext_vector_type(4))) float;

__device__ __forceinline__ float wsum(float v) {
    #pragma unroll
    for (int off = 32; off > 0; off >>= 1) v += __shfl_xor(v, off, 64);
    return v;
}

__device__ __forceinline__ unsigned short f2bf(float x) {   // RNE
    unsigned u = __float_as_uint(x);
    unsigned r = (u + 0x7FFFu + ((u >> 16) & 1u)) >> 16;
    return (unsigned short)r;
}

// ---------------- logmap0 of embeddings -> t (16 lanes/row, float4) ----------------
__global__ __launch_bounds__(256) void k_logmap(const float* __restrict__ eu, const float* __restrict__ ei,
                                                int Nu, int Ntot, float* __restrict__ out) {
    const int lane = threadIdx.x & 63;
    const int g = lane >> 4, q = lane & 15;
    const int n = blockIdx.x * 16 + (threadIdx.x >> 6) * 4 + g;
    if (n >= Ntot) return;
    const float* src = (n < Nu) ? (eu + (size_t)n * 64) : (ei + (size_t)(n - Nu) * 64);
    const float x0 = src[0];
    const float alpha = fmaxf(x0, 1.0f + EPSF);
    const float coef = acoshf(alpha) / sqrtf(fmaxf(alpha * alpha - 1.0f, EPSF));
    const float4 v = *(const float4*)(src + q * 4);
    float4 o;
    o.x = (q == 0) ? 0.0f : coef * v.x;
    o.y = coef * v.y; o.z = coef * v.z; o.w = coef * v.w;
    *(float4*)(out + ((size_t)n << 6) + q * 4) = o;
}

// ---------------- weight prep: W (E,D,O) fp32 -> Wt (E,O,D) bf16; b (E,O) -> Bt (O,E) bf16 ----------------
__global__ __launch_bounds__(256) void k_prep(const float* __restrict__ W, const float* __restrict__ Bb,
                                              unsigned short* __restrict__ Wt, unsigned short* __restrict__ Bt) {
    const int i = blockIdx.x * 256 + threadIdx.x;
    if (i < 4096) {
        const int e = i >> 9, o = (i >> 3) & 63, db = i & 7;
        unsigned short v[8];
        #pragma unroll
        for (int j = 0; j < 8; ++j)
            v[j] = f2bf(W[((size_t)e << 12) + (size_t)(db * 8 + j) * 64 + o]);
        uint4 p;
        p.x = (unsigned)v[0] | ((unsigned)v[1] << 16);
        p.y = (unsigned)v[2] | ((unsigned)v[3] << 16);
        p.z = (unsigned)v[4] | ((unsigned)v[5] << 16);
        p.w = (unsigned)v[6] | ((unsigned)v[7] << 16);
        *(uint4*)(Wt + (((size_t)(e * 64 + o)) << 6) + db * 8) = p;
    } else if (i < 4096 + 512) {
        const int j = i - 4096, o = j >> 3, e = j & 7;
        Bt[o * 8 + e] = f2bf(Bb[e * 64 + o]);
    }
}

// ---------------- MoE via MFMA: gate-folded GEMM, 64 nodes/block, 4 waves ----------------
__global__ __launch_bounds__(256) void k_moe_mfma(
    const float* __restrict__ X, float* __restrict__ Y,
    const unsigned short* __restrict__ Wt, const unsigned short* __restrict__ Bt,
    const float* __restrict__ GW, const float* __restrict__ GB, int Ntot)
{
    __shared__ float sX[64][68];
    __shared__ float sG[64][8];
    __shared__ float sGW[512];
    const int tid = threadIdx.x;
    const int n0 = blockIdx.x * 64;

    for (int i = tid; i < 64 * 16; i += 256) {
        const int rr = i >> 4, cc = i & 15;
        float4 v = make_float4(0.f, 0.f, 0.f, 0.f);
        if (n0 + rr < Ntot) v = *(const float4*)(X + (size_t)(n0 + rr) * 64 + cc * 4);
        *(float4*)&sX[rr][cc * 4] = v;
    }
    for (int i = tid; i < 512; i += 256) sGW[i] = GW[i];
    __syncthreads();

    {   // gating logits: thread -> node tid>>2, experts (tid&3)*2 .. +1
        const int n = tid >> 2, e0 = (tid & 3) * 2;
        float lg0 = GB[e0], lg1 = GB[e0 + 1];
        #pragma unroll 8
        for (int d = 0; d < 64; ++d) {
            const float xv = sX[n][d];
            lg0 += xv * sGW[d * 8 + e0];
            lg1 += xv * sGW[d * 8 + e0 + 1];
        }
        sG[n][e0] = lg0; sG[n][e0 + 1] = lg1;
    }
    __syncthreads();
    if (tid < 64) {
        float ex[8], mx = -1e30f, s = 0.f;
        #pragma unroll
        for (int e = 0; e < 8; ++e) mx = fmaxf(mx, sG[tid][e]);
        #pragma unroll
        for (int e = 0; e < 8; ++e) { ex[e] = expf(sG[tid][e] - mx); s += ex[e]; }
        const float inv = 1.0f / s;
        #pragma unroll
        for (int e = 0; e < 8; ++e) sG[tid][e] = ex[e] * inv;
    }
    __syncthreads();

    const int w = tid >> 6, l = tid & 63;
    const int m = l & 15, kq = l >> 4;
    const int rowm = w * 16 + m;

    f32x4 zero = {0.f, 0.f, 0.f, 0.f};
    f32x4 acc0 = zero, acc1 = zero, acc2 = zero, acc3 = zero;

    #pragma unroll
    for (int kk = 0; kk < 16; ++kk) {
        const int e = kk >> 1;
        const int d0 = (kk & 1) * 32 + kq * 8;
        const float gme = sG[rowm][e];
        const float4 xa = *(const float4*)&sX[rowm][d0];
        const float4 xb = *(const float4*)&sX[rowm][d0 + 4];
        union { bf16x8 v; unsigned short u[8]; } af;
        af.u[0] = f2bf(gme * xa.x); af.u[1] = f2bf(gme * xa.y);
        af.u[2] = f2bf(gme * xa.z); af.u[3] = f2bf(gme * xa.w);
        af.u[4] = f2bf(gme * xb.x); af.u[5] = f2bf(gme * xb.y);
        af.u[6] = f2bf(gme * xb.z); af.u[7] = f2bf(gme * xb.w);
        const unsigned short* wb = Wt + (((size_t)e * 64) << 6) + d0;
        const bf16x8 bf0 = *(const bf16x8*)(wb + ((0 * 16 + m) << 6));
        const bf16x8 bf1 = *(const bf16x8*)(wb + ((1 * 16 + m) << 6));
        const bf16x8 bf2 = *(const bf16x8*)(wb + ((2 * 16 + m) << 6));
        const bf16x8 bf3 = *(const bf16x8*)(wb + ((3 * 16 + m) << 6));
        acc0 = __builtin_amdgcn_mfma_f32_16x16x32_bf16(af.v, bf0, acc0, 0, 0, 0);
        acc1 = __builtin_amdgcn_mfma_f32_16x16x32_bf16(af.v, bf1, acc1, 0, 0, 0);
        acc2 = __builtin_amdgcn_mfma_f32_16x16x32_bf16(af.v, bf2, acc2, 0, 0, 0);
        acc3 = __builtin_amdgcn_mfma_f32_16x16x32_bf16(af.v, bf3, acc3, 0, 0, 0);
    }
    {   // bias K-step: A = gates, B = Bt
        union { bf16x8 v; unsigned short u[8]; } af;
        #pragma unroll
        for (int j = 0; j < 8; ++j) af.u[j] = (kq == 0) ? f2bf(sG[rowm][j]) : (unsigned short)0;
        bf16x8 z8 = {0, 0, 0, 0, 0, 0, 0, 0};
        bf16x8 b0 = z8, b1 = z8, b2 = z8, b3 = z8;
        if (kq == 0) {
            b0 = *(const bf16x8*)(Bt + ((0 * 16 + m) << 3));
            b1 = *(const bf16x8*)(Bt + ((1 * 16 + m) << 3));
            b2 = *(const bf16x8*)(Bt + ((2 * 16 + m) << 3));
            b3 = *(const bf16x8*)(Bt + ((3 * 16 + m) << 3));
        }
        acc0 = __builtin_amdgcn_mfma_f32_16x16x32_bf16(af.v, b0, acc0, 0, 0, 0);
        acc1 = __builtin_amdgcn_mfma_f32_16x16x32_bf16(af.v, b1, acc1, 0, 0, 0);
        acc2 = __builtin_amdgcn_mfma_f32_16x16x32_bf16(af.v, b2, acc2, 0, 0, 0);
        acc3 = __builtin_amdgcn_mfma_f32_16x16x32_bf16(af.v, b3, acc3, 0, 0, 0);
    }

    #pragma unroll
    for (int r = 0; r < 4; ++r) {
        const int mr = w * 16 + kq * 4 + r;
        if (n0 + mr < Ntot) {
            float* yr = Y + (size_t)(n0 + mr) * 64 + m;
            yr[0]  = acc0[r];
            yr[16] = acc1[r];
            yr[32] = acc2[r];
            yr[48] = acc3[r];
        }
    }
}

// ---------------- VAE mid ----------------
__global__ __launch_bounds__(256) void k_vae(
    const float* __restrict__ M, float* __restrict__ Hout,
    const float* __restrict__ EPSN,
    const float* __restrict__ muW, const float* __restrict__ mub,
    const float* __restrict__ lvW, const float* __restrict__ lvb,
    float* __restrict__ klslot)
{
    __shared__ float sM[32][68];
    __shared__ float sC[32];
    const int tid = threadIdx.x;
    const int n0 = blockIdx.x * 32;

    for (int i = tid; i < 2048; i += 256)
        sM[i >> 6][i & 63] = M[(size_t)n0 * 64 + i];
    __syncthreads();

    const int o = tid & 63, nq = tid >> 6;
    float ymu[8], ylv[8];
    #pragma unroll
    for (int k = 0; k < 8; ++k) { ymu[k] = 0.f; ylv[k] = 0.f; }

    for (int dc = 0; dc < 16; ++dc) {
        float a[8][4];
        #pragma unroll
        for (int k = 0; k < 8; ++k) {
            float4 av = *(const float4*)(&sM[nq + 4 * k][dc * 4]);
            a[k][0] = av.x; a[k][1] = av.y; a[k][2] = av.z; a[k][3] = av.w;
        }
        #pragma unroll
        for (int j = 0; j < 4; ++j) {
            const float wm = muW[(size_t)(dc * 4 + j) * 64 + o];
            const float wl = lvW[(size_t)(dc * 4 + j) * 64 + o];
            #pragma unroll
            for (int k = 0; k < 8; ++k) { ymu[k] += a[k][j] * wm; ylv[k] += a[k][j] * wl; }
        }
    }

    float u[8];
    float klp = 0.f;
    #pragma unroll
    for (int k = 0; k < 8; ++k) {
        const int n = nq + 4 * k;
        const float mu = ymu[k] + mub[o];
        const float lv = ylv[k] + lvb[o];
        const float elv = expf(lv);
        klp += 1.0f + lv - mu * mu - elv;
        u[k] = mu + EPSN[(size_t)(n0 + n) * 64 + o] * expf(0.5f * lv);
    }
    klp = wsum(klp);
    if ((tid & 63) == 0) atomicAdd(&klslot[(blockIdx.x * 4 + nq) & 255], klp);

    __syncthreads();
    #pragma unroll
    for (int k = 0; k < 8; ++k) sM[nq + 4 * k][o] = u[k];
    __syncthreads();

    {   // per-row norm: 8 lanes per row
        const int r2 = tid >> 3, j = tid & 7;
        const float4 a = *(const float4*)(&sM[r2][j * 8]);
        const float4 b = *(const float4*)(&sM[r2][j * 8 + 4]);
        const float ax = (j == 0) ? 0.f : a.x;
        float ss = ax * ax + a.y * a.y + a.z * a.z + a.w * a.w
                 + b.x * b.x + b.y * b.y + b.z * b.z + b.w * b.w;
        #pragma unroll
        for (int off = 1; off < 8; off <<= 1) ss += __shfl_xor(ss, off, 64);
        if (j == 0) {
            const float nr = fmaxf(sqrtf(ss), EPSF);
            const float r = sinhf(nr) / nr;
            const float sn = r * sqrtf(ss);
            const float scale = fminf(1.0f, MAXNRM / fmaxf(sn, EPSF));
            const float mult = r * scale;
            const float s2 = mult * mult * ss;
            const float z0 = sqrtf(1.0f + s2);
            const float alpha = fmaxf(z0, 1.0f + EPSF);
            const float coef = acoshf(alpha) / sqrtf(fmaxf(alpha * alpha - 1.0f, EPSF));
            sC[r2] = coef * mult;
        }
    }
    __syncthreads();

    #pragma unroll
    for (int k = 0; k < 8; ++k) {
        const int n = nq + 4 * k;
        Hout[(size_t)(n0 + n) * 64 + o] = (o == 0) ? 0.f : sC[n] * sM[n][o];
    }
}

// ---------------- FFN ----------------
__global__ __launch_bounds__(256) void k_ffn(
    float* __restrict__ Hio,
    const float* __restrict__ f1W, const float* __restrict__ f1b,
    const float* __restrict__ f2W, const float* __restrict__ f2b)
{
    __shared__ float sH[32][68];
    __shared__ float sH1[32][132];
    const int tid = threadIdx.x;
    const int n0 = blockIdx.x * 32;

    for (int i = tid; i < 2048; i += 256)
        sH[i >> 6][i & 63] = Hio[(size_t)n0 * 64 + i];
    __syncthreads();

    const int o = tid & 63, nq = tid >> 6;
    float y0[8], y1[8];
    #pragma unroll
    for (int k = 0; k < 8; ++k) { y0[k] = 0.f; y1[k] = 0.f; }

    for (int dc = 0; dc < 16; ++dc) {
        float a[8][4];
        #pragma unroll
        for (int k = 0; k < 8; ++k) {
            float4 av = *(const float4*)(&sH[nq + 4 * k][dc * 4]);
            a[k][0] = av.x; a[k][1] = av.y; a[k][2] = av.z; a[k][3] = av.w;
        }
        #pragma unroll
        for (int j = 0; j < 4; ++j) {
            const float w0 = f1W[(size_t)(dc * 4 + j) * 128 + o];
            const float w1 = f1W[(size_t)(dc * 4 + j) * 128 + 64 + o];
            #pragma unroll
            for (int k = 0; k < 8; ++k) { y0[k] += a[k][j] * w0; y1[k] += a[k][j] * w1; }
        }
    }
    #pragma unroll
    for (int k = 0; k < 8; ++k) {
        const int n = nq + 4 * k;
        sH1[n][o] = fmaxf(y0[k] + f1b[o], 0.f);
        sH1[n][64 + o] = fmaxf(y1[k] + f1b[64 + o], 0.f);
    }
    __syncthreads();

    float y2[8];
    #pragma unroll
    for (int k = 0; k < 8; ++k) y2[k] = 0.f;
    for (int dc = 0; dc < 32; ++dc) {
        float a[8][4];
        #pragma unroll
        for (int k = 0; k < 8; ++k) {
            float4 av = *(const float4*)(&sH1[nq + 4 * k][dc * 4]);
            a[k][0] = av.x; a[k][1] = av.y; a[k][2] = av.z; a[k][3] = av.w;
        }
        #pragma unroll
        for (int j = 0; j < 4; ++j) {
            const float w = f2W[(size_t)(dc * 4 + j) * 64 + o];
            #pragma unroll
            for (int k = 0; k < 8; ++k) y2[k] += a[k][j] * w;
        }
    }
    #pragma unroll
    for (int k = 0; k < 8; ++k)
        Hio[(size_t)(n0 + nq + 4 * k) * 64 + o] = y2[k] + f2b[o];
}

// ---------------- recon loss: 16 lanes/node, dot-product identity ----------------
__global__ __launch_bounds__(256) void k_recon(
    const float* __restrict__ HM, const float* __restrict__ M,
    int Ntot, float* __restrict__ slot)
{
    const int lane = threadIdx.x & 63;
    const int g = lane >> 4, q = lane & 15;
    const int n = blockIdx.x * 16 + (threadIdx.x >> 6) * 4 + g;

    float ssh = 0.f, ssm = 0.f, dot = 0.f;
    if (n < Ntot) {
        const float4 h = *(const float4*)(HM + ((size_t)n << 6) + q * 4);
        const float4 m = *(const float4*)(M  + ((size_t)n << 6) + q * 4);
        const float hx = (q == 0) ? 0.f : h.x;
        const float mx = (q == 0) ? 0.f : m.x;
        ssh = hx * hx + h.y * h.y + h.z * h.z + h.w * h.w;
        ssm = mx * mx + m.y * m.y + m.z * m.z + m.w * m.w;
        dot = hx * mx + h.y * m.y + h.z * m.z + h.w * m.w;
    }
    #pragma unroll
    for (int off = 1; off < 16; off <<= 1) {
        ssh += __shfl_xor(ssh, off, 64);
        ssm += __shfl_xor(ssm, off, 64);
        dot += __shfl_xor(dot, off, 64);
    }

    float part = 0.f;
    if (q == 0 && n < Ntot) {
        const float nm = fmaxf(sqrtf(ssm), EPSF);
        const float em0 = coshf(nm);
        const float rm = sinhf(nm) / nm;

        const float nh = fmaxf(sqrtf(ssh), EPSF);
        const float rh = sinhf(nh) / nh;
        const float sn = rh * sqrtf(ssh);
        const float scale = fminf(1.0f, MAXNRM / fmaxf(sn, EPSF));
        const float mult = rh * scale;
        const float rec0 = sqrtf(1.0f + mult * mult * ssh);

        const float inner = mult * rm * dot - rec0 * em0;
        const float dd = acoshf(fmaxf(-inner, 1.0f + EPSF));
        part = dd * dd;
    }
    part = wsum(part);
    __shared__ float sb[4];
    if (lane == 0) sb[threadIdx.x >> 6] = part;
    __syncthreads();
    if (threadIdx.x == 0)
        atomicAdd(&slot[blockIdx.x & 255], sb[0] + sb[1] + sb[2] + sb[3]);
}

// ---------------- bucket histogram ----------------
__global__ __launch_bounds__(256) void k_bhist(const int* __restrict__ rows, int nnz,
                                               int* __restrict__ bhist) {
    __shared__ int h[NB];
    for (int j = threadIdx.x; j < NB; j += 256) h[j] = 0;
    __syncthreads();
    for (int i = blockIdx.x * 256 + threadIdx.x; i < nnz; i += gridDim.x * 256)
        atomicAdd(&h[rows[i] >> 7], 1);
    __syncthreads();
    for (int j = threadIdx.x; j < NB; j += 256)
        if (h[j]) atomicAdd(&bhist[j], h[j]);
}

// ---------------- bucket scan (1 block) ----------------
__global__ __launch_bounds__(1024) void k_bscan(const int* __restrict__ bhist,
                                                int* __restrict__ bstart, int* __restrict__ gcur) {
    __shared__ int s[1024];
    const int tid = threadIdx.x;
    int v = (tid < NB) ? bhist[tid] : 0;
    s[tid] = v;
    __syncthreads();
    for (int off = 1; off < 1024; off <<= 1) {
        int t = (tid >= off) ? s[tid - off] : 0;
        __syncthreads();
        s[tid] += t;
        __syncthreads();
    }
    if (tid < NB) {
        bstart[tid + 1] = s[tid];
        gcur[tid] = s[tid] - v;
        if (tid == 0) bstart[0] = 0;
    }
}

// ---------------- stage-1 bucket scatter, LDS-aggregated cursors ----------------
__global__ __launch_bounds__(256) void k_bscatter(
    const int* __restrict__ rows, const int* __restrict__ cols,
    const float* __restrict__ vals, int nnz,
    int* __restrict__ gcur, int2* __restrict__ tmp)
{
    __shared__ int lh[NB];
    __shared__ int lb[NB];
    const int tid = threadIdx.x;
    for (int j = tid; j < NB; j += 256) lh[j] = 0;
    __syncthreads();

    const int base = blockIdx.x * (256 * EPT);
    int r[EPT], c[EPT], lp[EPT];
    float v[EPT];
    #pragma unroll
    for (int j = 0; j < EPT; ++j) {
        const int i = base + j * 256 + tid;
        if (i < nnz) {
            r[j] = rows[i]; c[j] = cols[i]; v[j] = vals[i];
            lp[j] = atomicAdd(&lh[r[j] >> 7], 1);
        }
    }
    __syncthreads();
    for (int j = tid; j < NB; j += 256)
        if (lh[j]) lb[j] = atomicAdd(&gcur[j], lh[j]);
    __syncthreads();
    #pragma unroll
    for (int j = 0; j < EPT; ++j) {
        const int i = base + j * 256 + tid;
        if (i < nnz) {
            int2 e;
            e.x = ((r[j] & 127) << 17) | c[j];
            e.y = __float_as_int(v[j]);
            tmp[lb[r[j] >> 7] + lp[j]] = e;
        }
    }
}

// ---------------- stage-2: two-pass CSR placement + F derivation ----------------
__global__ __launch_bounds__(256) void k_sort(
    const int2* __restrict__ tmp, const int* __restrict__ bstart,
    int2* __restrict__ sedge, int* __restrict__ Fout, int Ntot, int nnz)
{
    __shared__ int cnt[RPB];
    __shared__ int excl[RPB];
    const int b = blockIdx.x;
    const int tid = threadIdx.x;
    if (tid < RPB) cnt[tid] = 0;
    __syncthreads();
    const int s = bstart[b], t = bstart[b + 1];

    for (int i = s + tid; i < t; i += 256)
        atomicAdd(&cnt[((unsigned)tmp[i].x) >> 17], 1);
    __syncthreads();

    if (tid < 64) {
        const int a0 = cnt[2 * tid], a1 = cnt[2 * tid + 1];
        const int pairsum = a0 + a1;
        int run = pairsum;
        #pragma unroll
        for (int off = 1; off < 64; off <<= 1) {
            const int vv = __shfl_up(run, off, 64);
            if (tid >= off) run += vv;
        }
        const int ep = run - pairsum;
        excl[2 * tid] = ep;
        excl[2 * tid + 1] = ep + a0;
    }
    __syncthreads();

    const int r0 = b << 7;
    if (tid < RPB) {
        const int r = r0 + tid;
        if (r < Ntot) Fout[r] = s + excl[tid];
        cnt[tid] = excl[tid];
    }
    if (b == NB - 1 && tid == 0) Fout[Ntot] = nnz;
    __syncthreads();

    for (int i = s + tid; i < t; i += 256) {
        const int2 e = tmp[i];
        const int rib = ((unsigned)e.x) >> 17;
        const int lpos = atomicAdd(&cnt[rib], 1);
        int2 o; o.x = e.x & 0x1FFFF; o.y = e.y;
        sedge[s + lpos] = o;
    }
}

// ---------------- fp32 -> bf16 table copy ----------------
__global__ void k_tobf16(const float* __restrict__ in, unsigned short* __restrict__ out, int n8) {
    const int i = blockIdx.x * 256 + threadIdx.x;
    if (i >= n8) return;
    const float4 a = ((const float4*)in)[2 * i];
    const float4 b = ((const float4*)in)[2 * i + 1];
    uint4 p;
    p.x = (unsigned)f2bf(a.x) | ((unsigned)f2bf(a.y) << 16);
    p.y = (unsigned)f2bf(a.z) | ((unsigned)f2bf(a.w) << 16);
    p.z = (unsigned)f2bf(b.x) | ((unsigned)f2bf(b.y) << 16);
    p.w = (unsigned)f2bf(b.z) | ((unsigned)f2bf(b.w) << 16);
    ((uint4*)out)[i] = p;
}

// ---------------- SpMM: row per wave, bf16 gather, fp32 accumulate ----------------
template <int MODE>
__global__ __launch_bounds__(256) void k_spmm(
    const unsigned short* __restrict__ in, unsigned short* __restrict__ outb,
    float* __restrict__ osum,
    const int* __restrict__ F, const int2* __restrict__ sedge, int Ntot)
{
    const int r = blockIdx.x * 4 + (threadIdx.x >> 6);
    if (r >= Ntot) return;
    const int lane = threadIdx.x & 63;
    const int g = lane >> 3, q = lane & 7;
    const int e0 = F[r], e1 = F[r + 1];

    float acc0[8], acc1[8];
    #pragma unroll
    for (int j = 0; j < 8; ++j) { acc0[j] = 0.f; acc1[j] = 0.f; }

    for (int base = e0; base < e1; base += 16) {
        const int ea = base + g, eb = base + 8 + g;
        if (ea < e1) {
            const int2 ed = sedge[ea];
            const float v = __int_as_float(ed.y);
            const uint4 hb = *(const uint4*)(in + (((size_t)ed.x) << 6) + q * 8);
            acc0[0] += v * __uint_as_float(hb.x << 16);
            acc0[1] += v * __uint_as_float(hb.x & 0xFFFF0000u);
            acc0[2] += v * __uint_as_float(hb.y << 16);
            acc0[3] += v * __uint_as_float(hb.y & 0xFFFF0000u);
            acc0[4] += v * __uint_as_float(hb.z << 16);
            acc0[5] += v * __uint_as_float(hb.z & 0xFFFF0000u);
            acc0[6] += v * __uint_as_float(hb.w << 16);
            acc0[7] += v * __uint_as_float(hb.w & 0xFFFF0000u);
        }
        if (eb < e1) {
            const int2 ed = sedge[eb];
            const float v = __int_as_float(ed.y);
            const uint4 hb = *(const uint4*)(in + (((size_t)ed.x) << 6) + q * 8);
            acc1[0] += v * __uint_as_float(hb.x << 16);
            acc1[1] += v * __uint_as_float(hb.x & 0xFFFF0000u);
            acc1[2] += v * __uint_as_float(hb.y << 16);
            acc1[3] += v * __uint_as_float(hb.y & 0xFFFF0000u);
            acc1[4] += v * __uint_as_float(hb.z << 16);
            acc1[5] += v * __uint_as_float(hb.z & 0xFFFF0000u);
            acc1[6] += v * __uint_as_float(hb.w << 16);
            acc1[7] += v * __uint_as_float(hb.w & 0xFFFF0000u);
        }
    }
    #pragma unroll
    for (int j = 0; j < 8; ++j) acc0[j] += acc1[j];

    #pragma unroll
    for (int off = 8; off < 64; off <<= 1)
        #pragma unroll
        for (int j = 0; j < 8; ++j) acc0[j] += __shfl_xor(acc0[j], off, 64);

    if (g == 0) {
        const size_t ob = (((size_t)r) << 6) + q * 8;
        uint4 p;
        p.x = (unsigned)f2bf(acc0[0]) | ((unsigned)f2bf(acc0[1]) << 16);
        p.y = (unsigned)f2bf(acc0[2]) | ((unsigned)f2bf(acc0[3]) << 16);
        p.z = (unsigned)f2bf(acc0[4]) | ((unsigned)f2bf(acc0[5]) << 16);
        p.w = (unsigned)f2bf(acc0[6]) | ((unsigned)f2bf(acc0[7]) << 16);
        *(uint4*)(outb + ob) = p;

        float4 lo = make_float4(acc0[0], acc0[1], acc0[2], acc0[3]);
        float4 hi = make_float4(acc0[4], acc0[5], acc0[6], acc0[7]);
        if (MODE == 0) {
            *(float4*)(osum + ob) = lo;
            *(float4*)(osum + ob + 4) = hi;
        } else {
            float4 a = *(const float4*)(osum + ob);
            float4 b = *(const float4*)(osum + ob + 4);
            a.x += lo.x; a.y += lo.y; a.z += lo.z; a.w += lo.w;
            b.x += hi.x; b.y += hi.y; b.z += hi.z; b.w += hi.w;
            *(float4*)(osum + ob) = a;
            *(float4*)(osum + ob + 4) = b;
        }
    }
}

// ---------------- expmap0(out_sum, project=True): 16 lanes/row, float4 ----------------
__global__ __launch_bounds__(256) void k_expmap_proj(const float* __restrict__ in,
                                                     float* __restrict__ out, int Ntot) {
    const int lane = threadIdx.x & 63;
    const int g = lane >> 4, q = lane & 15;
    const int n = blockIdx.x * 16 + (threadIdx.x >> 6) * 4 + g;
    if (n >= Ntot) return;
    const float4 v = *(const float4*)(in + ((size_t)n << 6) + q * 4);
    const float vx = (q == 0) ? 0.f : v.x;
    float ss = vx * vx + v.y * v.y + v.z * v.z + v.w * v.w;
    #pragma unroll
    for (int off = 1; off < 16; off <<= 1) ss += __shfl_xor(ss, off, 64);
    const float nr = fmaxf(sqrtf(ss), EPSF);
    const float r = sinhf(nr) / nr;
    const float sn = r * sqrtf(ss);
    const float scale = fminf(1.0f, MAXNRM / fmaxf(sn, EPSF));
    const float mult = r * scale;
    float4 o;
    o.x = (q == 0) ? sqrtf(1.0f + mult * mult * ss) : mult * v.x;
    o.y = mult * v.y; o.z = mult * v.z; o.w = mult * v.w;
    *(float4*)(out + ((size_t)n << 6) + q * 4) = o;
}

// ---------------- triple margin loss ----------------
__global__ __launch_bounds__(256) void k_triples(
    const float* __restrict__ O, const int* __restrict__ tri,
    int T, float* __restrict__ slot)
{
    const int lane = threadIdx.x & 63;
    const int g = lane >> 4, q = lane & 15;
    const int wid = blockIdx.x * 4 + (threadIdx.x >> 6);
    const int nwaves = gridDim.x * 4;

    float racc = 0.f;
    for (int tb = wid * 4; tb < T; tb += nwaves * 4) {
        const int t = tb + g;
        const int a = tri[3 * t], p = tri[3 * t + 1], nn = tri[3 * t + 2];
        const float4 av = *(const float4*)(O + (((size_t)a) << 6) + q * 4);
        const float4 pv = *(const float4*)(O + (((size_t)p) << 6) + q * 4);
        const float4 nv = *(const float4*)(O + (((size_t)nn) << 6) + q * 4);
        const float s0 = (q == 0) ? -1.f : 1.f;
        float i1 = s0 * av.x * pv.x + av.y * pv.y + av.z * pv.z + av.w * pv.w;
        float i2 = s0 * av.x * nv.x + av.y * nv.y + av.z * nv.z + av.w * nv.w;
        #pragma unroll
        for (int off = 1; off < 16; off <<= 1) {
            i1 += __shfl_xor(i1, off, 64);
            i2 += __shfl_xor(i2, off, 64);
        }
        if (q == 0) {
            const float d1 = acoshf(fmaxf(-i1, 1.0f + EPSF));
            const float d2 = acoshf(fmaxf(-i2, 1.0f + EPSF));
            const float l = d1 * d1 - d2 * d2 + 0.1f;
            if (l > 0.f) racc += l;
        }
    }

    racc = wsum(racc);
    __shared__ float sb[4];
    if (lane == 0) sb[threadIdx.x >> 6] = racc;
    __syncthreads();
    if (threadIdx.x == 0)
        atomicAdd(&slot[blockIdx.x & 255], sb[0] + sb[1] + sb[2] + sb[3]);
}

// ---------------- finalize ----------------
__global__ void k_final(const float* __restrict__ slots, float* __restrict__ out, int Ntot)
{
    const int tid = threadIdx.x;
    float m = slots[tid], r = slots[256 + tid], k = slots[512 + tid];
    m = wsum(m); r = wsum(r); k = wsum(k);
    __shared__ float sm[4], sr[4], sk[4];
    if ((tid & 63) == 0) { sm[tid >> 6] = m; sr[tid >> 6] = r; sk[tid >> 6] = k; }
    __syncthreads();
    if (tid == 0) {
        const float M = sm[0] + sm[1] + sm[2] + sm[3];
        const float R = sr[0] + sr[1] + sr[2] + sr[3];
        const float K = sk[0] + sk[1] + sk[2] + sk[3];
        const float recon = R / (float)Ntot;
        const float kl = -0.5f * K / ((float)Ntot * 64.0f);
        out[0] = M + 0.1f * (recon + kl);
    }
}

extern "C" void kernel_launch(void* const* d_in, const int* in_sizes, int n_in,
                              void* d_out, int out_size, void* d_ws, size_t ws_size,
                              hipStream_t stream)
{
    const float* emb_user = (const float*)d_in[0];
    const float* emb_item = (const float*)d_in[1];
    const int*   adj_rows = (const int*)d_in[2];
    const int*   adj_cols = (const int*)d_in[3];
    const float* adj_vals = (const float*)d_in[4];
    const int*   triples  = (const int*)d_in[5];
    const float* epsin    = (const float*)d_in[6];
    const float* tW  = (const float*)d_in[7];
    const float* tb  = (const float*)d_in[8];
    const float* tgW = (const float*)d_in[9];
    const float* tgb = (const float*)d_in[10];
    const float* muW = (const float*)d_in[11];
    const float* mub = (const float*)d_in[12];
    const float* lvW = (const float*)d_in[13];
    const float* lvb = (const float*)d_in[14];
    const float* f1W = (const float*)d_in[15];
    const float* f1b = (const float*)d_in[16];
    const float* f2W = (const float*)d_in[17];
    const float* f2b = (const float*)d_in[18];
    const float* dW  = (const float*)d_in[19];
    const float* db  = (const float*)d_in[20];
    const float* dgW = (const float*)d_in[21];
    const float* dgb = (const float*)d_in[22];

    const int Nu = in_sizes[0] / 64, Ni = in_sizes[1] / 64;
    const int N = Nu + Ni;            // 100000
    const int NNZ = in_sizes[4];      // 3200000
    const int T = in_sizes[5] / 3;    // 262144

    float* ws = (float*)d_ws;
    size_t off = 0;
    float* slots = ws + off; off += 1024;            // margin / recon / kl slots
    float* A  = ws + off; off += (size_t)N * 64;     // t/h ; then stage-1 tmp edges; then bf16 {Bh, Hb1}
    float* B  = ws + off; off += (size_t)N * 64;     // m ; then O (expmap output)
    float* C  = ws + off; off += (size_t)N * 64;     // hm ; then out_sum (fp32)
    float* D  = ws + off; off += (size_t)N * 64;     // sedge (exact CSR int2[NNZ])
    float* Hb2f = ws + off; off += (size_t)N * 32;   // bf16 pong buffer
    int*   F  = (int*)(ws + off); off += (size_t)N + 64;   // row starts
    int*   bstart = (int*)(ws + off); off += 1024;
    int*   bhist  = (int*)(ws + off); off += 1024;
    int*   gcur   = (int*)(ws + off); off += 1024;
    unsigned short* Wt1 = (unsigned short*)(ws + off); off += 16384;  // 8x64x64 bf16
    unsigned short* Bt1 = (unsigned short*)(ws + off); off += 256;    // 64x8 bf16
    unsigned short* Wt2 = (unsigned short*)(ws + off); off += 16384;
    unsigned short* Bt2 = (unsigned short*)(ws + off); off += 256;

    int2* tmp   = (int2*)A;
    int2* sedge = (int2*)D;
    unsigned short* Bh  = (unsigned short*)A;
    unsigned short* Hb1 = (unsigned short*)A + (size_t)N * 64;
    unsigned short* Hb2 = (unsigned short*)Hb2f;

    hipMemsetAsync(slots, 0, 1024 * sizeof(float), stream);
    hipMemsetAsync(bhist, 0, 1024 * sizeof(int), stream);

    const int nb32 = N / 32;          // 3125
    const int nb16 = (N + 15) / 16;   // 6250
    const int nb64 = (N + 63) / 64;   // 1563

    // weight prep for both MoEs
    k_prep<<<18, 256, 0, stream>>>(tW, tb, Wt1, Bt1);
    k_prep<<<18, 256, 0, stream>>>(dW, db, Wt2, Bt2);

    // dense chain
    k_logmap<<<nb16, 256, 0, stream>>>(emb_user, emb_item, Nu, N, A);
    k_moe_mfma<<<nb64, 256, 0, stream>>>(A, B, Wt1, Bt1, tgW, tgb, N);
    k_vae<<<nb32, 256, 0, stream>>>(B, A, epsin, muW, mub, lvW, lvb, slots + 512);
    k_ffn<<<nb32, 256, 0, stream>>>(A, f1W, f1b, f2W, f2b);
    k_moe_mfma<<<nb64, 256, 0, stream>>>(A, C, Wt2, Bt2, dgW, dgb, N);
    k_recon<<<nb16, 256, 0, stream>>>(C, B, N, slots + 256);

    // CSR build (bucket-local)
    k_bhist<<<512, 256, 0, stream>>>(adj_rows, NNZ, bhist);
    k_bscan<<<1, 1024, 0, stream>>>(bhist, bstart, gcur);
    const int ns1 = (NNZ + 256 * EPT - 1) / (256 * EPT);   // 782
    k_bscatter<<<ns1, 256, 0, stream>>>(adj_rows, adj_cols, adj_vals, NNZ, gcur, tmp);
    k_sort<<<NB, 256, 0, stream>>>(tmp, bstart, sedge, F, N, NNZ);

    // bf16 table for layer-1 gather
    k_tobf16<<<(N * 64 / 8 + 255) / 256, 256, 0, stream>>>(B, Bh, N * 8);

    // 3-layer spmm chain
    k_spmm<0><<<(N + 3) / 4, 256, 0, stream>>>(Bh,  Hb1, C, F, sedge, N);
    k_spmm<1><<<(N + 3) / 4, 256, 0, stream>>>(Hb1, Hb2, C, F, sedge, N);
    k_spmm<1><<<(N + 3) / 4, 256, 0, stream>>>(Hb2, Bh,  C, F, sedge, N);

    k_expmap_proj<<<nb16, 256, 0, stream>>>(C, B, N);
    k_triples<<<2048, 256, 0, stream>>>(B, triples, T, slots);
    k_final<<<1, 256, 0, stream>>>(slots, (float*)d_out, N);
}

// Round 8
// 621.299 us; speedup vs baseline: 8.6956x; 1.0649x over previous
//
#include <hip/hip_runtime.h>
#include <math.h>

#define EPSF 1e-7f
#define MAXNRM 10.0f
#define NB 782          // ceil(100000/128) buckets
#define RPB 128         // rows per bucket
#define EPT 16          // edges per thread in stage-1 scatter

using bf16x8 = __attribute__((ext_vector_type(8))) short;
using f32x4  = __attribute__((ext_vector_type(4))) float;

__device__ __forceinline__ float wsum(float v) {
    #pragma unroll
    for (int off = 32; off > 0; off >>= 1) v += __shfl_xor(v, off, 64);
    return v;
}

__device__ __forceinline__ unsigned short f2bf(float x) {   // RNE
    unsigned u = __float_as_uint(x);
    unsigned r = (u + 0x7FFFu + ((u >> 16) & 1u)) >> 16;
    return (unsigned short)r;
}
__device__ __forceinline__ float bflo(unsigned u) { return __uint_as_float(u << 16); }
__device__ __forceinline__ float bfhi(unsigned u) { return __uint_as_float(u & 0xFFFF0000u); }

// ---------------- logmap0 of embeddings -> t (16 lanes/row, float4) ----------------
__global__ __launch_bounds__(256) void k_logmap(const float* __restrict__ eu, const float* __restrict__ ei,
                                                int Nu, int Ntot, float* __restrict__ out) {
    const int lane = threadIdx.x & 63;
    const int g = lane >> 4, q = lane & 15;
    const int n = blockIdx.x * 16 + (threadIdx.x >> 6) * 4 + g;
    if (n >= Ntot) return;
    const float* src = (n < Nu) ? (eu + (size_t)n * 64) : (ei + (size_t)(n - Nu) * 64);
    const float x0 = src[0];
    const float alpha = fmaxf(x0, 1.0f + EPSF);
    const float coef = acoshf(alpha) / sqrtf(fmaxf(alpha * alpha - 1.0f, EPSF));
    const float4 v = *(const float4*)(src + q * 4);
    float4 o;
    o.x = (q == 0) ? 0.0f : coef * v.x;
    o.y = coef * v.y; o.z = coef * v.z; o.w = coef * v.w;
    *(float4*)(out + ((size_t)n << 6) + q * 4) = o;
}

// ---------------- MoE weight prep: W (E,D,O) fp32 -> Wt (E,O,D) bf16; b -> Bt (O,E) ----------------
__global__ __launch_bounds__(256) void k_prep(const float* __restrict__ W, const float* __restrict__ Bb,
                                              unsigned short* __restrict__ Wt, unsigned short* __restrict__ Bt) {
    const int i = blockIdx.x * 256 + threadIdx.x;
    if (i < 4096) {
        const int e = i >> 9, o = (i >> 3) & 63, db = i & 7;
        unsigned short v[8];
        #pragma unroll
        for (int j = 0; j < 8; ++j)
            v[j] = f2bf(W[((size_t)e << 12) + (size_t)(db * 8 + j) * 64 + o]);
        uint4 p;
        p.x = (unsigned)v[0] | ((unsigned)v[1] << 16);
        p.y = (unsigned)v[2] | ((unsigned)v[3] << 16);
        p.z = (unsigned)v[4] | ((unsigned)v[5] << 16);
        p.w = (unsigned)v[6] | ((unsigned)v[7] << 16);
        *(uint4*)(Wt + (((size_t)(e * 64 + o)) << 6) + db * 8) = p;
    } else if (i < 4096 + 512) {
        const int j = i - 4096, o = j >> 3, e = j & 7;
        Bt[o * 8 + e] = f2bf(Bb[e * 64 + o]);
    }
}

// ---------------- generic transpose prep: src[K][O] fp32 -> dst[O][K] bf16 ----------------
__global__ __launch_bounds__(256) void k_prepw(const float* __restrict__ src,
                                               unsigned short* __restrict__ dst, int K, int O) {
    const int i = blockIdx.x * 256 + threadIdx.x;
    if (i >= K * O) return;
    const int o = i / K, k = i - o * K;
    dst[i] = f2bf(src[k * O + o]);
}

// ---------------- MoE via MFMA: gate-folded GEMM, 64 nodes/block, 4 waves ----------------
__global__ __launch_bounds__(256) void k_moe_mfma(
    const float* __restrict__ X, float* __restrict__ Y,
    const unsigned short* __restrict__ Wt, const unsigned short* __restrict__ Bt,
    const float* __restrict__ GW, const float* __restrict__ GB, int Ntot)
{
    __shared__ float sX[64][68];
    __shared__ float sG[64][8];
    __shared__ float sGW[512];
    const int tid = threadIdx.x;
    const int n0 = blockIdx.x * 64;

    for (int i = tid; i < 64 * 16; i += 256) {
        const int rr = i >> 4, cc = i & 15;
        float4 v = make_float4(0.f, 0.f, 0.f, 0.f);
        if (n0 + rr < Ntot) v = *(const float4*)(X + (size_t)(n0 + rr) * 64 + cc * 4);
        *(float4*)&sX[rr][cc * 4] = v;
    }
    for (int i = tid; i < 512; i += 256) sGW[i] = GW[i];
    __syncthreads();

    {
        const int n = tid >> 2, e0 = (tid & 3) * 2;
        float lg0 = GB[e0], lg1 = GB[e0 + 1];
        #pragma unroll 8
        for (int d = 0; d < 64; ++d) {
            const float xv = sX[n][d];
            lg0 += xv * sGW[d * 8 + e0];
            lg1 += xv * sGW[d * 8 + e0 + 1];
        }
        sG[n][e0] = lg0; sG[n][e0 + 1] = lg1;
    }
    __syncthreads();
    if (tid < 64) {
        float ex[8], mx = -1e30f, s = 0.f;
        #pragma unroll
        for (int e = 0; e < 8; ++e) mx = fmaxf(mx, sG[tid][e]);
        #pragma unroll
        for (int e = 0; e < 8; ++e) { ex[e] = expf(sG[tid][e] - mx); s += ex[e]; }
        const float inv = 1.0f / s;
        #pragma unroll
        for (int e = 0; e < 8; ++e) sG[tid][e] = ex[e] * inv;
    }
    __syncthreads();

    const int w = tid >> 6, l = tid & 63;
    const int m = l & 15, kq = l >> 4;
    const int rowm = w * 16 + m;

    f32x4 zero = {0.f, 0.f, 0.f, 0.f};
    f32x4 acc0 = zero, acc1 = zero, acc2 = zero, acc3 = zero;

    #pragma unroll
    for (int kk = 0; kk < 16; ++kk) {
        const int e = kk >> 1;
        const int d0 = (kk & 1) * 32 + kq * 8;
        const float gme = sG[rowm][e];
        const float4 xa = *(const float4*)&sX[rowm][d0];
        const float4 xb = *(const float4*)&sX[rowm][d0 + 4];
        union { bf16x8 v; unsigned short u[8]; } af;
        af.u[0] = f2bf(gme * xa.x); af.u[1] = f2bf(gme * xa.y);
        af.u[2] = f2bf(gme * xa.z); af.u[3] = f2bf(gme * xa.w);
        af.u[4] = f2bf(gme * xb.x); af.u[5] = f2bf(gme * xb.y);
        af.u[6] = f2bf(gme * xb.z); af.u[7] = f2bf(gme * xb.w);
        const unsigned short* wb = Wt + (((size_t)e * 64) << 6) + d0;
        const bf16x8 bf0 = *(const bf16x8*)(wb + ((0 * 16 + m) << 6));
        const bf16x8 bf1 = *(const bf16x8*)(wb + ((1 * 16 + m) << 6));
        const bf16x8 bf2 = *(const bf16x8*)(wb + ((2 * 16 + m) << 6));
        const bf16x8 bf3 = *(const bf16x8*)(wb + ((3 * 16 + m) << 6));
        acc0 = __builtin_amdgcn_mfma_f32_16x16x32_bf16(af.v, bf0, acc0, 0, 0, 0);
        acc1 = __builtin_amdgcn_mfma_f32_16x16x32_bf16(af.v, bf1, acc1, 0, 0, 0);
        acc2 = __builtin_amdgcn_mfma_f32_16x16x32_bf16(af.v, bf2, acc2, 0, 0, 0);
        acc3 = __builtin_amdgcn_mfma_f32_16x16x32_bf16(af.v, bf3, acc3, 0, 0, 0);
    }
    {
        union { bf16x8 v; unsigned short u[8]; } af;
        #pragma unroll
        for (int j = 0; j < 8; ++j) af.u[j] = (kq == 0) ? f2bf(sG[rowm][j]) : (unsigned short)0;
        bf16x8 z8 = {0, 0, 0, 0, 0, 0, 0, 0};
        bf16x8 b0 = z8, b1 = z8, b2 = z8, b3 = z8;
        if (kq == 0) {
            b0 = *(const bf16x8*)(Bt + ((0 * 16 + m) << 3));
            b1 = *(const bf16x8*)(Bt + ((1 * 16 + m) << 3));
            b2 = *(const bf16x8*)(Bt + ((2 * 16 + m) << 3));
            b3 = *(const bf16x8*)(Bt + ((3 * 16 + m) << 3));
        }
        acc0 = __builtin_amdgcn_mfma_f32_16x16x32_bf16(af.v, b0, acc0, 0, 0, 0);
        acc1 = __builtin_amdgcn_mfma_f32_16x16x32_bf16(af.v, b1, acc1, 0, 0, 0);
        acc2 = __builtin_amdgcn_mfma_f32_16x16x32_bf16(af.v, b2, acc2, 0, 0, 0);
        acc3 = __builtin_amdgcn_mfma_f32_16x16x32_bf16(af.v, b3, acc3, 0, 0, 0);
    }

    #pragma unroll
    for (int r = 0; r < 4; ++r) {
        const int mr = w * 16 + kq * 4 + r;
        if (n0 + mr < Ntot) {
            float* yr = Y + (size_t)(n0 + mr) * 64 + m;
            yr[0]  = acc0[r];
            yr[16] = acc1[r];
            yr[32] = acc2[r];
            yr[48] = acc3[r];
        }
    }
}

// ---------------- VAE via MFMA: [mu|lv] GEMM + reparam + logmap(expmap) epilogue ----------------
__global__ __launch_bounds__(256) void k_vae_mfma(
    const float* __restrict__ M, float* __restrict__ Hout,
    const float* __restrict__ EPSN, const unsigned short* __restrict__ WtV,
    const float* __restrict__ mub, const float* __restrict__ lvb,
    float* __restrict__ klslot, int Ntot)
{
    __shared__ float sX[64][68];
    __shared__ float sC[64];
    const int tid = threadIdx.x;
    const int n0 = blockIdx.x * 64;

    for (int i = tid; i < 64 * 16; i += 256) {
        const int rr = i >> 4, cc = i & 15;
        float4 v = make_float4(0.f, 0.f, 0.f, 0.f);
        if (n0 + rr < Ntot) v = *(const float4*)(M + (size_t)(n0 + rr) * 64 + cc * 4);
        *(float4*)&sX[rr][cc * 4] = v;
    }
    __syncthreads();

    const int w = tid >> 6, l = tid & 63;
    const int m = l & 15, kq = l >> 4;
    const int rowm = w * 16 + m;

    f32x4 zero = {0.f, 0.f, 0.f, 0.f};
    f32x4 acc[8];
    #pragma unroll
    for (int t = 0; t < 8; ++t) acc[t] = zero;

    #pragma unroll
    for (int ks = 0; ks < 2; ++ks) {
        const int k0 = ks * 32 + kq * 8;
        const float4 xa = *(const float4*)&sX[rowm][k0];
        const float4 xb = *(const float4*)&sX[rowm][k0 + 4];
        union { bf16x8 v; unsigned short u[8]; } af;
        af.u[0] = f2bf(xa.x); af.u[1] = f2bf(xa.y); af.u[2] = f2bf(xa.z); af.u[3] = f2bf(xa.w);
        af.u[4] = f2bf(xb.x); af.u[5] = f2bf(xb.y); af.u[6] = f2bf(xb.z); af.u[7] = f2bf(xb.w);
        #pragma unroll
        for (int t = 0; t < 8; ++t) {
            const bf16x8 bf = *(const bf16x8*)(WtV + (((size_t)(t * 16 + m)) << 6) + k0);
            acc[t] = __builtin_amdgcn_mfma_f32_16x16x32_bf16(af.v, bf, acc[t], 0, 0, 0);
        }
    }

    float klp = 0.f;
    float uv[4][4];
    #pragma unroll
    for (int t = 0; t < 4; ++t) {
        const int col = t * 16 + m;
        const float mb = mub[col], lb = lvb[col];
        #pragma unroll
        for (int r = 0; r < 4; ++r) {
            const int row = w * 16 + kq * 4 + r;
            const float mu = acc[t][r] + mb;
            const float lv = acc[t + 4][r] + lb;
            const float elv = expf(lv);
            float ep = 0.f;
            if (n0 + row < Ntot) {
                klp += 1.0f + lv - mu * mu - elv;
                ep = EPSN[(size_t)(n0 + row) * 64 + col];
            }
            uv[t][r] = mu + ep * expf(0.5f * lv);
        }
    }
    klp = wsum(klp);
    if (l == 0) atomicAdd(&klslot[(blockIdx.x * 4 + w) & 255], klp);

    // write u back into sX (wave-local rows only)
    #pragma unroll
    for (int t = 0; t < 4; ++t)
        #pragma unroll
        for (int r = 0; r < 4; ++r)
            sX[w * 16 + kq * 4 + r][t * 16 + m] = uv[t][r];
    __syncthreads();

    {   // per-row norm: 4 lanes per row (64 rows x 4 lanes = 256 threads)
        const int r2 = tid >> 2, j = tid & 3;
        float ss = 0.f;
        #pragma unroll
        for (int jj = 0; jj < 4; ++jj) {
            float4 a = *(const float4*)&sX[r2][j * 16 + jj * 4];
            if (j == 0 && jj == 0) a.x = 0.f;
            ss += a.x * a.x + a.y * a.y + a.z * a.z + a.w * a.w;
        }
        ss += __shfl_xor(ss, 1, 64);
        ss += __shfl_xor(ss, 2, 64);
        if (j == 0) {
            const float nr = fmaxf(sqrtf(ss), EPSF);
            const float r = sinhf(nr) / nr;
            const float sn = r * sqrtf(ss);
            const float scale = fminf(1.0f, MAXNRM / fmaxf(sn, EPSF));
            const float mult = r * scale;
            const float s2 = mult * mult * ss;
            const float z0 = sqrtf(1.0f + s2);
            const float alpha = fmaxf(z0, 1.0f + EPSF);
            const float coef = acoshf(alpha) / sqrtf(fmaxf(alpha * alpha - 1.0f, EPSF));
            sC[r2] = coef * mult;
        }
    }
    __syncthreads();

    for (int i = tid; i < 64 * 16; i += 256) {
        const int rr = i >> 4, cc = i & 15;
        if (n0 + rr >= Ntot) continue;
        const float4 v = *(const float4*)&sX[rr][cc * 4];
        const float sc = sC[rr];
        float4 o;
        o.x = (cc == 0) ? 0.f : sc * v.x;
        o.y = sc * v.y; o.z = sc * v.z; o.w = sc * v.w;
        *(float4*)(Hout + (size_t)(n0 + rr) * 64 + cc * 4) = o;
    }
}

// ---------------- FFN via MFMA: relu(h@f1W+f1b)@f2W+f2b, in-place ----------------
__global__ __launch_bounds__(256) void k_ffn_mfma(
    float* __restrict__ Hio,
    const unsigned short* __restrict__ Wt1f, const float* __restrict__ f1b,
    const unsigned short* __restrict__ Wt2f, const float* __restrict__ f2b, int Ntot)
{
    __shared__ float sH[64][68];
    __shared__ unsigned short sH1[64][136];
    const int tid = threadIdx.x;
    const int n0 = blockIdx.x * 64;

    for (int i = tid; i < 64 * 16; i += 256) {
        const int rr = i >> 4, cc = i & 15;
        float4 v = make_float4(0.f, 0.f, 0.f, 0.f);
        if (n0 + rr < Ntot) v = *(const float4*)(Hio + (size_t)(n0 + rr) * 64 + cc * 4);
        *(float4*)&sH[rr][cc * 4] = v;
    }
    __syncthreads();

    const int w = tid >> 6, l = tid & 63;
    const int m = l & 15, kq = l >> 4;
    const int rowm = w * 16 + m;

    f32x4 zero = {0.f, 0.f, 0.f, 0.f};
    f32x4 acc1[8];
    #pragma unroll
    for (int t = 0; t < 8; ++t) acc1[t] = zero;

    #pragma unroll
    for (int ks = 0; ks < 2; ++ks) {
        const int k0 = ks * 32 + kq * 8;
        const float4 xa = *(const float4*)&sH[rowm][k0];
        const float4 xb = *(const float4*)&sH[rowm][k0 + 4];
        union { bf16x8 v; unsigned short u[8]; } af;
        af.u[0] = f2bf(xa.x); af.u[1] = f2bf(xa.y); af.u[2] = f2bf(xa.z); af.u[3] = f2bf(xa.w);
        af.u[4] = f2bf(xb.x); af.u[5] = f2bf(xb.y); af.u[6] = f2bf(xb.z); af.u[7] = f2bf(xb.w);
        #pragma unroll
        for (int t = 0; t < 8; ++t) {
            const bf16x8 bf = *(const bf16x8*)(Wt1f + (((size_t)(t * 16 + m)) << 6) + k0);
            acc1[t] = __builtin_amdgcn_mfma_f32_16x16x32_bf16(af.v, bf, acc1[t], 0, 0, 0);
        }
    }
    #pragma unroll
    for (int t = 0; t < 8; ++t) {
        const float bb = f1b[t * 16 + m];
        #pragma unroll
        for (int r = 0; r < 4; ++r)
            sH1[w * 16 + kq * 4 + r][t * 16 + m] = f2bf(fmaxf(acc1[t][r] + bb, 0.f));
    }
    __syncthreads();

    f32x4 acc2[4];
    #pragma unroll
    for (int t = 0; t < 4; ++t) acc2[t] = zero;
    #pragma unroll
    for (int ks = 0; ks < 4; ++ks) {
        const int k0 = ks * 32 + kq * 8;
        const bf16x8 af = *(const bf16x8*)&sH1[rowm][k0];
        #pragma unroll
        for (int t = 0; t < 4; ++t) {
            const bf16x8 bf = *(const bf16x8*)(Wt2f + (((size_t)(t * 16 + m)) << 7) + k0);
            acc2[t] = __builtin_amdgcn_mfma_f32_16x16x32_bf16(af, bf, acc2[t], 0, 0, 0);
        }
    }
    #pragma unroll
    for (int t = 0; t < 4; ++t) {
        const float bb = f2b[t * 16 + m];
        #pragma unroll
        for (int r = 0; r < 4; ++r) {
            const int row = w * 16 + kq * 4 + r;
            if (n0 + row < Ntot)
                Hio[(size_t)(n0 + row) * 64 + t * 16 + m] = acc2[t][r] + bb;
        }
    }
}

// ---------------- recon loss: 16 lanes/node, dot-product identity ----------------
__global__ __launch_bounds__(256) void k_recon(
    const float* __restrict__ HM, const float* __restrict__ M,
    int Ntot, float* __restrict__ slot)
{
    const int lane = threadIdx.x & 63;
    const int g = lane >> 4, q = lane & 15;
    const int n = blockIdx.x * 16 + (threadIdx.x >> 6) * 4 + g;

    float ssh = 0.f, ssm = 0.f, dot = 0.f;
    if (n < Ntot) {
        const float4 h = *(const float4*)(HM + ((size_t)n << 6) + q * 4);
        const float4 m = *(const float4*)(M  + ((size_t)n << 6) + q * 4);
        const float hx = (q == 0) ? 0.f : h.x;
        const float mx = (q == 0) ? 0.f : m.x;
        ssh = hx * hx + h.y * h.y + h.z * h.z + h.w * h.w;
        ssm = mx * mx + m.y * m.y + m.z * m.z + m.w * m.w;
        dot = hx * mx + h.y * m.y + h.z * m.z + h.w * m.w;
    }
    #pragma unroll
    for (int off = 1; off < 16; off <<= 1) {
        ssh += __shfl_xor(ssh, off, 64);
        ssm += __shfl_xor(ssm, off, 64);
        dot += __shfl_xor(dot, off, 64);
    }

    float part = 0.f;
    if (q == 0 && n < Ntot) {
        const float nm = fmaxf(sqrtf(ssm), EPSF);
        const float em0 = coshf(nm);
        const float rm = sinhf(nm) / nm;

        const float nh = fmaxf(sqrtf(ssh), EPSF);
        const float rh = sinhf(nh) / nh;
        const float sn = rh * sqrtf(ssh);
        const float scale = fminf(1.0f, MAXNRM / fmaxf(sn, EPSF));
        const float mult = rh * scale;
        const float rec0 = sqrtf(1.0f + mult * mult * ssh);

        const float inner = mult * rm * dot - rec0 * em0;
        const float dd = acoshf(fmaxf(-inner, 1.0f + EPSF));
        part = dd * dd;
    }
    part = wsum(part);
    __shared__ float sb[4];
    if (lane == 0) sb[threadIdx.x >> 6] = part;
    __syncthreads();
    if (threadIdx.x == 0)
        atomicAdd(&slot[blockIdx.x & 255], sb[0] + sb[1] + sb[2] + sb[3]);
}

// ---------------- bucket histogram ----------------
__global__ __launch_bounds__(256) void k_bhist(const int* __restrict__ rows, int nnz,
                                               int* __restrict__ bhist) {
    __shared__ int h[NB];
    for (int j = threadIdx.x; j < NB; j += 256) h[j] = 0;
    __syncthreads();
    for (int i = blockIdx.x * 256 + threadIdx.x; i < nnz; i += gridDim.x * 256)
        atomicAdd(&h[rows[i] >> 7], 1);
    __syncthreads();
    for (int j = threadIdx.x; j < NB; j += 256)
        if (h[j]) atomicAdd(&bhist[j], h[j]);
}

// ---------------- bucket scan (1 block) ----------------
__global__ __launch_bounds__(1024) void k_bscan(const int* __restrict__ bhist,
                                                int* __restrict__ bstart, int* __restrict__ gcur) {
    __shared__ int s[1024];
    const int tid = threadIdx.x;
    int v = (tid < NB) ? bhist[tid] : 0;
    s[tid] = v;
    __syncthreads();
    for (int off = 1; off < 1024; off <<= 1) {
        int t = (tid >= off) ? s[tid - off] : 0;
        __syncthreads();
        s[tid] += t;
        __syncthreads();
    }
    if (tid < NB) {
        bstart[tid + 1] = s[tid];
        gcur[tid] = s[tid] - v;
        if (tid == 0) bstart[0] = 0;
    }
}

// ---------------- stage-1 bucket scatter, LDS-aggregated cursors ----------------
__global__ __launch_bounds__(256) void k_bscatter(
    const int* __restrict__ rows, const int* __restrict__ cols,
    const float* __restrict__ vals, int nnz,
    int* __restrict__ gcur, int2* __restrict__ tmp)
{
    __shared__ int lh[NB];
    __shared__ int lb[NB];
    const int tid = threadIdx.x;
    for (int j = tid; j < NB; j += 256) lh[j] = 0;
    __syncthreads();

    const int base = blockIdx.x * (256 * EPT);
    int r[EPT], c[EPT], lp[EPT];
    float v[EPT];
    #pragma unroll
    for (int j = 0; j < EPT; ++j) {
        const int i = base + j * 256 + tid;
        if (i < nnz) {
            r[j] = rows[i]; c[j] = cols[i]; v[j] = vals[i];
            lp[j] = atomicAdd(&lh[r[j] >> 7], 1);
        }
    }
    __syncthreads();
    for (int j = tid; j < NB; j += 256)
        if (lh[j]) lb[j] = atomicAdd(&gcur[j], lh[j]);
    __syncthreads();
    #pragma unroll
    for (int j = 0; j < EPT; ++j) {
        const int i = base + j * 256 + tid;
        if (i < nnz) {
            int2 e;
            e.x = ((r[j] & 127) << 17) | c[j];
            e.y = __float_as_int(v[j]);
            tmp[lb[r[j] >> 7] + lp[j]] = e;
        }
    }
}

// ---------------- stage-2: two-pass CSR placement + F derivation ----------------
__global__ __launch_bounds__(256) void k_sort(
    const int2* __restrict__ tmp, const int* __restrict__ bstart,
    int2* __restrict__ sedge, int* __restrict__ Fout, int Ntot, int nnz)
{
    __shared__ int cnt[RPB];
    __shared__ int excl[RPB];
    const int b = blockIdx.x;
    const int tid = threadIdx.x;
    if (tid < RPB) cnt[tid] = 0;
    __syncthreads();
    const int s = bstart[b], t = bstart[b + 1];

    for (int i = s + tid; i < t; i += 256)
        atomicAdd(&cnt[((unsigned)tmp[i].x) >> 17], 1);
    __syncthreads();

    if (tid < 64) {
        const int a0 = cnt[2 * tid], a1 = cnt[2 * tid + 1];
        const int pairsum = a0 + a1;
        int run = pairsum;
        #pragma unroll
        for (int off = 1; off < 64; off <<= 1) {
            const int vv = __shfl_up(run, off, 64);
            if (tid >= off) run += vv;
        }
        const int ep = run - pairsum;
        excl[2 * tid] = ep;
        excl[2 * tid + 1] = ep + a0;
    }
    __syncthreads();

    const int r0 = b << 7;
    if (tid < RPB) {
        const int r = r0 + tid;
        if (r < Ntot) Fout[r] = s + excl[tid];
        cnt[tid] = excl[tid];
    }
    if (b == NB - 1 && tid == 0) Fout[Ntot] = nnz;
    __syncthreads();

    for (int i = s + tid; i < t; i += 256) {
        const int2 e = tmp[i];
        const int rib = ((unsigned)e.x) >> 17;
        const int lpos = atomicAdd(&cnt[rib], 1);
        int2 o; o.x = e.x & 0x1FFFF; o.y = e.y;
        sedge[s + lpos] = o;
    }
}

// ---------------- fp32 -> bf16 table copy ----------------
__global__ void k_tobf16(const float* __restrict__ in, unsigned short* __restrict__ out, int n8) {
    const int i = blockIdx.x * 256 + threadIdx.x;
    if (i >= n8) return;
    const float4 a = ((const float4*)in)[2 * i];
    const float4 b = ((const float4*)in)[2 * i + 1];
    uint4 p;
    p.x = (unsigned)f2bf(a.x) | ((unsigned)f2bf(a.y) << 16);
    p.y = (unsigned)f2bf(a.z) | ((unsigned)f2bf(a.w) << 16);
    p.z = (unsigned)f2bf(b.x) | ((unsigned)f2bf(b.y) << 16);
    p.w = (unsigned)f2bf(b.z) | ((unsigned)f2bf(b.w) << 16);
    ((uint4*)out)[i] = p;
}

// ---------------- SpMM: row per wave, bf16 gather, 32 edges in flight ----------------
template <int MODE>
__global__ __launch_bounds__(256) void k_spmm(
    const unsigned short* __restrict__ in, unsigned short* __restrict__ outb,
    float* __restrict__ osum,
    const int* __restrict__ F, const int2* __restrict__ sedge, int Ntot)
{
    const int r = blockIdx.x * 4 + (threadIdx.x >> 6);
    if (r >= Ntot) return;
    const int lane = threadIdx.x & 63;
    const int g = lane >> 3, q = lane & 7;
    const int e0 = F[r], e1 = F[r + 1];

    float acc[4][8];
    #pragma unroll
    for (int u = 0; u < 4; ++u)
        #pragma unroll
        for (int j = 0; j < 8; ++j) acc[u][j] = 0.f;

    for (int base = e0; base < e1; base += 32) {
        #pragma unroll
        for (int u = 0; u < 4; ++u) {
            const int e = base + u * 8 + g;
            if (e < e1) {
                const int2 ed = sedge[e];
                const float v = __int_as_float(ed.y);
                const uint4 hb = *(const uint4*)(in + (((size_t)ed.x) << 6) + q * 8);
                acc[u][0] += v * bflo(hb.x);
                acc[u][1] += v * bfhi(hb.x);
                acc[u][2] += v * bflo(hb.y);
                acc[u][3] += v * bfhi(hb.y);
                acc[u][4] += v * bflo(hb.z);
                acc[u][5] += v * bfhi(hb.z);
                acc[u][6] += v * bflo(hb.w);
                acc[u][7] += v * bfhi(hb.w);
            }
        }
    }
    float a0[8];
    #pragma unroll
    for (int j = 0; j < 8; ++j) a0[j] = (acc[0][j] + acc[1][j]) + (acc[2][j] + acc[3][j]);

    #pragma unroll
    for (int off = 8; off < 64; off <<= 1)
        #pragma unroll
        for (int j = 0; j < 8; ++j) a0[j] += __shfl_xor(a0[j], off, 64);

    if (g == 0) {
        const size_t ob = (((size_t)r) << 6) + q * 8;
        uint4 p;
        p.x = (unsigned)f2bf(a0[0]) | ((unsigned)f2bf(a0[1]) << 16);
        p.y = (unsigned)f2bf(a0[2]) | ((unsigned)f2bf(a0[3]) << 16);
        p.z = (unsigned)f2bf(a0[4]) | ((unsigned)f2bf(a0[5]) << 16);
        p.w = (unsigned)f2bf(a0[6]) | ((unsigned)f2bf(a0[7]) << 16);
        *(uint4*)(outb + ob) = p;

        float4 lo = make_float4(a0[0], a0[1], a0[2], a0[3]);
        float4 hi = make_float4(a0[4], a0[5], a0[6], a0[7]);
        if (MODE == 0) {
            *(float4*)(osum + ob) = lo;
            *(float4*)(osum + ob + 4) = hi;
        } else {
            float4 a = *(const float4*)(osum + ob);
            float4 b = *(const float4*)(osum + ob + 4);
            a.x += lo.x; a.y += lo.y; a.z += lo.z; a.w += lo.w;
            b.x += hi.x; b.y += hi.y; b.z += hi.z; b.w += hi.w;
            *(float4*)(osum + ob) = a;
            *(float4*)(osum + ob + 4) = b;
        }
    }
}

// ---------------- expmap0(out_sum, project=True) -> bf16 O ----------------
__global__ __launch_bounds__(256) void k_expmap_proj(const float* __restrict__ in,
                                                     unsigned short* __restrict__ outb, int Ntot) {
    const int lane = threadIdx.x & 63;
    const int g = lane >> 4, q = lane & 15;
    const int n = blockIdx.x * 16 + (threadIdx.x >> 6) * 4 + g;
    if (n >= Ntot) return;
    const float4 v = *(const float4*)(in + ((size_t)n << 6) + q * 4);
    const float vx = (q == 0) ? 0.f : v.x;
    float ss = vx * vx + v.y * v.y + v.z * v.z + v.w * v.w;
    #pragma unroll
    for (int off = 1; off < 16; off <<= 1) ss += __shfl_xor(ss, off, 64);
    const float nr = fmaxf(sqrtf(ss), EPSF);
    const float r = sinhf(nr) / nr;
    const float sn = r * sqrtf(ss);
    const float scale = fminf(1.0f, MAXNRM / fmaxf(sn, EPSF));
    const float mult = r * scale;
    float ox = (q == 0) ? sqrtf(1.0f + mult * mult * ss) : mult * v.x;
    uint2 p;
    p.x = (unsigned)f2bf(ox) | ((unsigned)f2bf(mult * v.y) << 16);
    p.y = (unsigned)f2bf(mult * v.z) | ((unsigned)f2bf(mult * v.w) << 16);
    *(uint2*)(outb + ((size_t)n << 6) + q * 4) = p;
}

// ---------------- triple margin loss (bf16 gather) ----------------
__global__ __launch_bounds__(256) void k_triples(
    const unsigned short* __restrict__ Ob, const int* __restrict__ tri,
    int T, float* __restrict__ slot)
{
    const int lane = threadIdx.x & 63;
    const int g = lane >> 4, q = lane & 15;
    const int wid = blockIdx.x * 4 + (threadIdx.x >> 6);
    const int nwaves = gridDim.x * 4;

    float racc = 0.f;
    for (int tb = wid * 4; tb < T; tb += nwaves * 4) {
        const int t = tb + g;
        const int a = tri[3 * t], p = tri[3 * t + 1], nn = tri[3 * t + 2];
        const uint2 ua = *(const uint2*)(Ob + (((size_t)a) << 6) + q * 4);
        const uint2 up = *(const uint2*)(Ob + (((size_t)p) << 6) + q * 4);
        const uint2 un = *(const uint2*)(Ob + (((size_t)nn) << 6) + q * 4);
        const float a0 = bflo(ua.x), a1 = bfhi(ua.x), a2 = bflo(ua.y), a3 = bfhi(ua.y);
        const float p0 = bflo(up.x), p1 = bfhi(up.x), p2 = bflo(up.y), p3 = bfhi(up.y);
        const float n0 = bflo(un.x), n1 = bfhi(un.x), n2 = bflo(un.y), n3 = bfhi(un.y);
        const float s0 = (q == 0) ? -1.f : 1.f;
        float i1 = s0 * a0 * p0 + a1 * p1 + a2 * p2 + a3 * p3;
        float i2 = s0 * a0 * n0 + a1 * n1 + a2 * n2 + a3 * n3;
        #pragma unroll
        for (int off = 1; off < 16; off <<= 1) {
            i1 += __shfl_xor(i1, off, 64);
            i2 += __shfl_xor(i2, off, 64);
        }
        if (q == 0) {
            const float d1 = acoshf(fmaxf(-i1, 1.0f + EPSF));
            const float d2 = acoshf(fmaxf(-i2, 1.0f + EPSF));
            const float l = d1 * d1 - d2 * d2 + 0.1f;
            if (l > 0.f) racc += l;
        }
    }

    racc = wsum(racc);
    __shared__ float sb[4];
    if (lane == 0) sb[threadIdx.x >> 6] = racc;
    __syncthreads();
    if (threadIdx.x == 0)
        atomicAdd(&slot[blockIdx.x & 255], sb[0] + sb[1] + sb[2] + sb[3]);
}

// ---------------- finalize ----------------
__global__ void k_final(const float* __restrict__ slots, float* __restrict__ out, int Ntot)
{
    const int tid = threadIdx.x;
    float m = slots[tid], r = slots[256 + tid], k = slots[512 + tid];
    m = wsum(m); r = wsum(r); k = wsum(k);
    __shared__ float sm[4], sr[4], sk[4];
    if ((tid & 63) == 0) { sm[tid >> 6] = m; sr[tid >> 6] = r; sk[tid >> 6] = k; }
    __syncthreads();
    if (tid == 0) {
        const float M = sm[0] + sm[1] + sm[2] + sm[3];
        const float R = sr[0] + sr[1] + sr[2] + sr[3];
        const float K = sk[0] + sk[1] + sk[2] + sk[3];
        const float recon = R / (float)Ntot;
        const float kl = -0.5f * K / ((float)Ntot * 64.0f);
        out[0] = M + 0.1f * (recon + kl);
    }
}

extern "C" void kernel_launch(void* const* d_in, const int* in_sizes, int n_in,
                              void* d_out, int out_size, void* d_ws, size_t ws_size,
                              hipStream_t stream)
{
    const float* emb_user = (const float*)d_in[0];
    const float* emb_item = (const float*)d_in[1];
    const int*   adj_rows = (const int*)d_in[2];
    const int*   adj_cols = (const int*)d_in[3];
    const float* adj_vals = (const float*)d_in[4];
    const int*   triples  = (const int*)d_in[5];
    const float* epsin    = (const float*)d_in[6];
    const float* tW  = (const float*)d_in[7];
    const float* tb  = (const float*)d_in[8];
    const float* tgW = (const float*)d_in[9];
    const float* tgb = (const float*)d_in[10];
    const float* muW = (const float*)d_in[11];
    const float* mub = (const float*)d_in[12];
    const float* lvW = (const float*)d_in[13];
    const float* lvb = (const float*)d_in[14];
    const float* f1W = (const float*)d_in[15];
    const float* f1b = (const float*)d_in[16];
    const float* f2W = (const float*)d_in[17];
    const float* f2b = (const float*)d_in[18];
    const float* dW  = (const float*)d_in[19];
    const float* db  = (const float*)d_in[20];
    const float* dgW = (const float*)d_in[21];
    const float* dgb = (const float*)d_in[22];

    const int Nu = in_sizes[0] / 64, Ni = in_sizes[1] / 64;
    const int N = Nu + Ni;            // 100000
    const int NNZ = in_sizes[4];      // 3200000
    const int T = in_sizes[5] / 3;    // 262144

    float* ws = (float*)d_ws;
    size_t off = 0;
    float* slots = ws + off; off += 1024;            // margin / recon / kl slots
    float* A  = ws + off; off += (size_t)N * 64;     // t/h ; then tmp edges; then bf16 {Bh, Hb1}
    float* B  = ws + off; off += (size_t)N * 64;     // m ; then Ob (bf16 expmap output)
    float* C  = ws + off; off += (size_t)N * 64;     // hm ; then out_sum (fp32)
    float* D  = ws + off; off += (size_t)N * 64;     // sedge (exact CSR int2[NNZ])
    float* Hb2f = ws + off; off += (size_t)N * 32;   // bf16 pong buffer
    int*   F  = (int*)(ws + off); off += (size_t)N + 64;   // row starts
    int*   bstart = (int*)(ws + off); off += 1024;
    int*   bhist  = (int*)(ws + off); off += 1024;
    int*   gcur   = (int*)(ws + off); off += 1024;
    unsigned short* Wt1 = (unsigned short*)(ws + off); off += 16384;  // MoE1 8x64x64
    unsigned short* Bt1 = (unsigned short*)(ws + off); off += 256;
    unsigned short* Wt2 = (unsigned short*)(ws + off); off += 16384;  // MoE2
    unsigned short* Bt2 = (unsigned short*)(ws + off); off += 256;
    unsigned short* WtV  = (unsigned short*)(ws + off); off += 4096;  // [mu|lv] 128x64 bf16
    unsigned short* Wt1f = (unsigned short*)(ws + off); off += 4096;  // f1W^T 128x64 bf16
    unsigned short* Wt2f = (unsigned short*)(ws + off); off += 4096;  // f2W^T 64x128 bf16

    int2* tmp   = (int2*)A;
    int2* sedge = (int2*)D;
    unsigned short* Bh  = (unsigned short*)A;
    unsigned short* Hb1 = (unsigned short*)A + (size_t)N * 64;
    unsigned short* Hb2 = (unsigned short*)Hb2f;
    unsigned short* Ob  = (unsigned short*)B;        // B dead after k_tobf16

    hipMemsetAsync(slots, 0, 1024 * sizeof(float), stream);
    hipMemsetAsync(bhist, 0, 1024 * sizeof(int), stream);

    const int nb16 = (N + 15) / 16;   // 6250
    const int nb64 = (N + 63) / 64;   // 1563

    // weight prep
    k_prep<<<18, 256, 0, stream>>>(tW, tb, Wt1, Bt1);
    k_prep<<<18, 256, 0, stream>>>(dW, db, Wt2, Bt2);
    k_prepw<<<16, 256, 0, stream>>>(muW, WtV, 64, 64);
    k_prepw<<<16, 256, 0, stream>>>(lvW, WtV + 4096, 64, 64);
    k_prepw<<<32, 256, 0, stream>>>(f1W, Wt1f, 64, 128);
    k_prepw<<<32, 256, 0, stream>>>(f2W, Wt2f, 128, 64);

    // dense chain
    k_logmap<<<nb16, 256, 0, stream>>>(emb_user, emb_item, Nu, N, A);
    k_moe_mfma<<<nb64, 256, 0, stream>>>(A, B, Wt1, Bt1, tgW, tgb, N);
    k_vae_mfma<<<nb64, 256, 0, stream>>>(B, A, epsin, WtV, mub, lvb, slots + 512, N);
    k_ffn_mfma<<<nb64, 256, 0, stream>>>(A, Wt1f, f1b, Wt2f, f2b, N);
    k_moe_mfma<<<nb64, 256, 0, stream>>>(A, C, Wt2, Bt2, dgW, dgb, N);
    k_recon<<<nb16, 256, 0, stream>>>(C, B, N, slots + 256);

    // CSR build (bucket-local)
    k_bhist<<<512, 256, 0, stream>>>(adj_rows, NNZ, bhist);
    k_bscan<<<1, 1024, 0, stream>>>(bhist, bstart, gcur);
    const int ns1 = (NNZ + 256 * EPT - 1) / (256 * EPT);   // 782
    k_bscatter<<<ns1, 256, 0, stream>>>(adj_rows, adj_cols, adj_vals, NNZ, gcur, tmp);
    k_sort<<<NB, 256, 0, stream>>>(tmp, bstart, sedge, F, N, NNZ);

    // bf16 table for layer-1 gather
    k_tobf16<<<(N * 64 / 8 + 255) / 256, 256, 0, stream>>>(B, Bh, N * 8);

    // 3-layer spmm chain
    k_spmm<0><<<(N + 3) / 4, 256, 0, stream>>>(Bh,  Hb1, C, F, sedge, N);
    k_spmm<1><<<(N + 3) / 4, 256, 0, stream>>>(Hb1, Hb2, C, F, sedge, N);
    k_spmm<1><<<(N + 3) / 4, 256, 0, stream>>>(Hb2, Bh,  C, F, sedge, N);

    k_expmap_proj<<<nb16, 256, 0, stream>>>(C, Ob, N);
    k_triples<<<2048, 256, 0, stream>>>(Ob, triples, T, slots);
    k_final<<<1, 256, 0, stream>>>(slots, (float*)d_out, N);
}